// Round 1
// baseline (968.110 us; speedup 1.0000x reference)
//
#include <hip/hip_runtime.h>

#define EMB 64

// ---------------------------------------------------------------------------
// Design notes (round 1, correctness-first fp32 baseline):
// - mean-aggregate commutes with the linear layer, so SAGEConv becomes:
//     t_src = x_src @ ll_w  (dense GEMM)
//     u_dst = x_dst @ lr_w  (dense GEMM, written into the destination buffer)
//     out   = relu(csr_mean_gather(t_src) + ll_b + u_dst)
// - CSR built per call (deterministic topology; neighbor order varies by
//   atomic scatter but only causes ~1e-5 fp reorder noise, far under threshold)
// - last layer: new_c is dead (output is x_v only) -> skipped entirely
// ---------------------------------------------------------------------------

__global__ __launch_bounds__(256) void zero_int_kernel(int* __restrict__ p, int n) {
    int i = blockIdx.x * 256 + threadIdx.x;
    if (i < n) p[i] = 0;
}

__global__ __launch_bounds__(256) void hist_kernel(const int* __restrict__ src, const int* __restrict__ dst,
                                                   int E, int* __restrict__ cnt_c, int* __restrict__ cnt_v) {
    int i = blockIdx.x * 256 + threadIdx.x;
    if (i < E) {
        atomicAdd(&cnt_v[dst[i]], 1);
        atomicAdd(&cnt_c[src[i]], 1);
    }
}

// per-block (2048 elems) exclusive scan; emits per-block totals
__global__ __launch_bounds__(256) void scan_blocks_kernel(const int* __restrict__ cnt, int* __restrict__ excl,
                                                          int* __restrict__ bsums, int n) {
    __shared__ int tot[256];
    int t = threadIdx.x;
    int base = blockIdx.x * 2048 + t * 8;
    int v[8];
    int s = 0;
#pragma unroll
    for (int i = 0; i < 8; ++i) { v[i] = (base + i < n) ? cnt[base + i] : 0; s += v[i]; }
    tot[t] = s;
    __syncthreads();
    for (int off = 1; off < 256; off <<= 1) {
        int x = (t >= off) ? tot[t - off] : 0;
        __syncthreads();
        tot[t] += x;
        __syncthreads();
    }
    int run = (t > 0) ? tot[t - 1] : 0;
#pragma unroll
    for (int i = 0; i < 8; ++i) {
        if (base + i < n) excl[base + i] = run;
        run += v[i];
    }
    if (t == 255) bsums[blockIdx.x] = tot[255];
}

// single-block exclusive scan of up to 256 block totals (in place)
__global__ __launch_bounds__(256) void scan_small_kernel(int* __restrict__ data, int n) {
    __shared__ int tot[256];
    int t = threadIdx.x;
    tot[t] = (t < n) ? data[t] : 0;
    __syncthreads();
    for (int off = 1; off < 256; off <<= 1) {
        int x = (t >= off) ? tot[t - off] : 0;
        __syncthreads();
        tot[t] += x;
        __syncthreads();
    }
    if (t < n) data[t] = (t > 0) ? tot[t - 1] : 0;
}

__global__ __launch_bounds__(256) void scan_add_kernel(int* __restrict__ rowptr, const int* __restrict__ bsums,
                                                       int n, int total) {
    int i = blockIdx.x * 256 + threadIdx.x;
    if (i < n) rowptr[i] += bsums[i >> 11];
    else if (i == n) rowptr[i] = total;
}

__global__ __launch_bounds__(256) void scatter_kernel(const int* __restrict__ src, const int* __restrict__ dst, int E,
                                                      const int* __restrict__ rp_c, const int* __restrict__ rp_v,
                                                      int* __restrict__ cur_c, int* __restrict__ cur_v,
                                                      int* __restrict__ adj_c, int* __restrict__ adj_v) {
    int i = blockIdx.x * 256 + threadIdx.x;
    if (i < E) {
        int s = src[i], d = dst[i];
        int pv = rp_v[d] + atomicAdd(&cur_v[d], 1);
        adj_v[pv] = s;
        int pc = rp_c[s] + atomicAdd(&cur_c[s], 1);
        adj_c[pc] = d;
    }
}

// h = relu(((x+shift)*scale) @ W1 + b1); one wave per row, lane = out column
__global__ __launch_bounds__(256) void embed1_kernel(
    const float* __restrict__ x, const float* __restrict__ shift, const float* __restrict__ scale,
    const float* __restrict__ w1, const float* __restrict__ b1,
    float* __restrict__ h, int n, int nf)
{
    __shared__ float w1s[19 * EMB];
    __shared__ float ssc[2 * 19];
    int tid = threadIdx.x;
    for (int i = tid; i < nf * EMB; i += 256) w1s[i] = w1[i];
    if (tid < nf) { ssc[tid] = shift[tid]; ssc[19 + tid] = scale[tid]; }
    __syncthreads();
    int lane = tid & 63;
    int row = blockIdx.x * 4 + (tid >> 6);
    if (row >= n) return;
    float acc = b1[lane];
    for (int k = 0; k < nf; ++k) {
        float xv = (x[(long)row * nf + k] + ssc[k]) * ssc[19 + k];
        acc = fmaf(xv, w1s[k * EMB + lane], acc);
    }
    h[(long)row * EMB + lane] = fmaxf(acc, 0.f);
}

// C1 = act(X@W1 [+B1]); optionally C2 = act(X@W2 [+B2]) sharing the X tile.
// C2 may alias X (tile fully staged to LDS before any store; blocks own
// disjoint 64-row ranges).
template <bool HAS2>
__global__ __launch_bounds__(256) void gemm64_kernel(
    const float* __restrict__ X, int n,
    const float* __restrict__ W1, const float* __restrict__ B1, int relu1, float* __restrict__ C1,
    const float* __restrict__ W2, const float* __restrict__ B2, int relu2, float* __restrict__ C2)
{
    __shared__ float xs[EMB * 68];            // transposed tile: xs[k*68 + r]
    __shared__ float w1s[EMB * EMB];
    __shared__ float w2s[HAS2 ? (EMB * EMB) : 4];

    int t = threadIdx.x;
    {
        int r = t >> 2;
        int cs = (t & 3) * 16;
        long gr = (long)blockIdx.x * 64 + r;
        float4 v[4];
        if (gr < n) {
            const float4* sp = (const float4*)(X + gr * EMB + cs);
#pragma unroll
            for (int q = 0; q < 4; ++q) v[q] = sp[q];
        } else {
            float4 z = make_float4(0.f, 0.f, 0.f, 0.f);
#pragma unroll
            for (int q = 0; q < 4; ++q) v[q] = z;
        }
#pragma unroll
        for (int q = 0; q < 4; ++q) {
            xs[(cs + q * 4 + 0) * 68 + r] = v[q].x;
            xs[(cs + q * 4 + 1) * 68 + r] = v[q].y;
            xs[(cs + q * 4 + 2) * 68 + r] = v[q].z;
            xs[(cs + q * 4 + 3) * 68 + r] = v[q].w;
        }
        const float4* wg1 = (const float4*)W1;
        float4* wl1 = (float4*)w1s;
#pragma unroll
        for (int q = 0; q < 4; ++q) wl1[t + q * 256] = wg1[t + q * 256];
        if (HAS2) {
            const float4* wg2 = (const float4*)W2;
            float4* wl2 = (float4*)w2s;
#pragma unroll
            for (int q = 0; q < 4; ++q) wl2[t + q * 256] = wg2[t + q * 256];
        }
    }
    __syncthreads();

    int r0 = (t >> 4) * 4;
    int c0 = (t & 15) * 4;
    float acc1[4][4] = {{0.f}};
    float acc2[4][4] = {{0.f}};
#pragma unroll 8
    for (int k = 0; k < EMB; ++k) {
        float4 xv = *(const float4*)&xs[k * 68 + r0];
        float4 wv = *(const float4*)&w1s[k * EMB + c0];
        float xa[4] = {xv.x, xv.y, xv.z, xv.w};
        float wa[4] = {wv.x, wv.y, wv.z, wv.w};
#pragma unroll
        for (int i = 0; i < 4; ++i)
#pragma unroll
            for (int j = 0; j < 4; ++j)
                acc1[i][j] = fmaf(xa[i], wa[j], acc1[i][j]);
        if (HAS2) {
            float4 w2v = *(const float4*)&w2s[k * EMB + c0];
            float wb[4] = {w2v.x, w2v.y, w2v.z, w2v.w};
#pragma unroll
            for (int i = 0; i < 4; ++i)
#pragma unroll
                for (int j = 0; j < 4; ++j)
                    acc2[i][j] = fmaf(xa[i], wb[j], acc2[i][j]);
        }
    }

    float4 b1v = make_float4(0.f, 0.f, 0.f, 0.f);
    if (B1) b1v = *(const float4*)&B1[c0];
#pragma unroll
    for (int i = 0; i < 4; ++i) {
        long gr = (long)blockIdx.x * 64 + r0 + i;
        if (gr < n) {
            float o0 = acc1[i][0] + b1v.x;
            float o1 = acc1[i][1] + b1v.y;
            float o2 = acc1[i][2] + b1v.z;
            float o3 = acc1[i][3] + b1v.w;
            if (relu1) { o0 = fmaxf(o0, 0.f); o1 = fmaxf(o1, 0.f); o2 = fmaxf(o2, 0.f); o3 = fmaxf(o3, 0.f); }
            *(float4*)&C1[gr * EMB + c0] = make_float4(o0, o1, o2, o3);
        }
    }
    if (HAS2) {
        float4 b2v = make_float4(0.f, 0.f, 0.f, 0.f);
        if (B2) b2v = *(const float4*)&B2[c0];
#pragma unroll
        for (int i = 0; i < 4; ++i) {
            long gr = (long)blockIdx.x * 64 + r0 + i;
            if (gr < n) {
                float o0 = acc2[i][0] + b2v.x;
                float o1 = acc2[i][1] + b2v.y;
                float o2 = acc2[i][2] + b2v.z;
                float o3 = acc2[i][3] + b2v.w;
                if (relu2) { o0 = fmaxf(o0, 0.f); o1 = fmaxf(o1, 0.f); o2 = fmaxf(o2, 0.f); o3 = fmaxf(o3, 0.f); }
                *(float4*)&C2[gr * EMB + c0] = make_float4(o0, o1, o2, o3);
            }
        }
    }
}

// out[node] = relu(mean_{nbr in CSR} t_src[nbr] + bias + out[node])
// wave per node; lane = feature; neighbor rows are coalesced 256B reads.
__global__ __launch_bounds__(256) void agg_kernel(
    const float* __restrict__ t_src, const int* __restrict__ rowptr, const int* __restrict__ adj,
    const float* __restrict__ bias, float* __restrict__ out, int n_dst)
{
    int lane = threadIdx.x & 63;
    int node = blockIdx.x * 4 + (threadIdx.x >> 6);
    if (node >= n_dst) return;
    int beg = rowptr[node];
    int end = rowptr[node + 1];
    float acc = 0.f;
    int e = beg;
    for (; e + 4 <= end; e += 4) {
        int n0 = adj[e + 0];
        int n1 = adj[e + 1];
        int n2 = adj[e + 2];
        int n3 = adj[e + 3];
        float v0 = t_src[n0 * EMB + lane];
        float v1 = t_src[n1 * EMB + lane];
        float v2 = t_src[n2 * EMB + lane];
        float v3 = t_src[n3 * EMB + lane];
        acc += (v0 + v1) + (v2 + v3);
    }
    for (; e < end; ++e) acc += t_src[adj[e] * EMB + lane];
    int cnt = end - beg;
    float mean = acc / (float)(cnt > 0 ? cnt : 1);
    float val = mean + bias[lane] + out[(long)node * EMB + lane];
    out[(long)node * EMB + lane] = fmaxf(val, 0.f);
}

extern "C" void kernel_launch(void* const* d_in, const int* in_sizes, int n_in,
                              void* d_out, int out_size, void* d_ws, size_t ws_size,
                              hipStream_t stream) {
    const float* cons_x     = (const float*)d_in[0];
    const float* var_x      = (const float*)d_in[1];
    const int*   eidx       = (const int*)d_in[3];
    const float* cons_shift = (const float*)d_in[4];
    const float* cons_scale = (const float*)d_in[5];
    const float* cons_w1    = (const float*)d_in[6];
    const float* cons_b1    = (const float*)d_in[7];
    const float* cons_w2    = (const float*)d_in[8];
    const float* cons_b2    = (const float*)d_in[9];
    const float* var_shift  = (const float*)d_in[10];
    const float* var_scale  = (const float*)d_in[11];
    const float* var_w1     = (const float*)d_in[12];
    const float* var_b1     = (const float*)d_in[13];
    const float* var_w2     = (const float*)d_in[14];
    const float* var_b2     = (const float*)d_in[15];
    const float* ll_w       = (const float*)d_in[18];
    const float* ll_b       = (const float*)d_in[19];
    const float* lr_w       = (const float*)d_in[20];

    const int nC = in_sizes[0] / 5;
    const int nV = in_sizes[1] / 19;
    const int E  = in_sizes[3] / 2;
    const int* src = eidx;       // constraint ids
    const int* dst = eidx + E;   // variable ids

    char* w = (char*)d_ws;
    auto alloc = [&](size_t bytes) {
        char* p = w;
        w += (bytes + 255) & ~(size_t)255;
        return p;
    };
    float* x_c = (float*)alloc((size_t)nC * EMB * 4);
    float* x_v = (float*)alloc((size_t)nV * EMB * 4);
    float* t_c = (float*)alloc((size_t)nC * EMB * 4);   // also embed hidden for cons
    float* t_v = (float*)alloc((size_t)nV * EMB * 4);   // also embed hidden for var
    int* rp_v  = (int*)alloc((size_t)(nV + 1) * 4);
    int* rp_c  = (int*)alloc((size_t)(nC + 1) * 4);
    int* cnts  = (int*)alloc((size_t)(nV + nC) * 2 * 4);  // cnt_v, cnt_c, cur_v, cur_c
    int* cnt_v = cnts;
    int* cnt_c = cnts + nV;
    int* cur_v = cnt_c + nC;
    int* cur_c = cur_v + nV;
    int* adj_v = (int*)alloc((size_t)E * 4);
    int* adj_c = (int*)alloc((size_t)E * 4);
    int* bs_v  = (int*)alloc(256 * 4);
    int* bs_c  = (int*)alloc(256 * 4);

    auto llw = [&](int l, int d) { return ll_w + (size_t)(l * 2 + d) * EMB * EMB; };
    auto lrw = [&](int l, int d) { return lr_w + (size_t)(l * 2 + d) * EMB * EMB; };
    auto llb = [&](int l, int d) { return ll_b + (size_t)(l * 2 + d) * EMB; };

    // ---- CSR build ----
    int nz = (nV + nC) * 2;
    zero_int_kernel<<<(nz + 255) / 256, 256, 0, stream>>>(cnts, nz);
    hist_kernel<<<(E + 255) / 256, 256, 0, stream>>>(src, dst, E, cnt_c, cnt_v);
    int Bv = (nV + 2047) / 2048, Bc = (nC + 2047) / 2048;
    scan_blocks_kernel<<<Bv, 256, 0, stream>>>(cnt_v, rp_v, bs_v, nV);
    scan_small_kernel<<<1, 256, 0, stream>>>(bs_v, Bv);
    scan_add_kernel<<<(nV + 1 + 255) / 256, 256, 0, stream>>>(rp_v, bs_v, nV, E);
    scan_blocks_kernel<<<Bc, 256, 0, stream>>>(cnt_c, rp_c, bs_c, nC);
    scan_small_kernel<<<1, 256, 0, stream>>>(bs_c, Bc);
    scan_add_kernel<<<(nC + 1 + 255) / 256, 256, 0, stream>>>(rp_c, bs_c, nC, E);
    scatter_kernel<<<(E + 255) / 256, 256, 0, stream>>>(src, dst, E, rp_c, rp_v, cur_c, cur_v, adj_c, adj_v);

    // ---- node embeddings ----
    embed1_kernel<<<(nC + 3) / 4, 256, 0, stream>>>(cons_x, cons_shift, cons_scale, cons_w1, cons_b1, t_c, nC, 5);
    gemm64_kernel<false><<<(nC + 63) / 64, 256, 0, stream>>>(t_c, nC, cons_w2, cons_b2, 1, x_c,
                                                             nullptr, nullptr, 0, nullptr);
    embed1_kernel<<<(nV + 3) / 4, 256, 0, stream>>>(var_x, var_shift, var_scale, var_w1, var_b1, t_v, nV, 19);
    gemm64_kernel<false><<<(nV + 63) / 64, 256, 0, stream>>>(t_v, nV, var_w2, var_b2, 1, x_v,
                                                             nullptr, nullptr, 0, nullptr);

    // ---- layer 0 (u-terms written in place into x_c / x_v) ----
    gemm64_kernel<true><<<(nC + 63) / 64, 256, 0, stream>>>(x_c, nC, llw(0, 0), nullptr, 0, t_c,
                                                            lrw(0, 1), nullptr, 0, x_c);
    gemm64_kernel<true><<<(nV + 63) / 64, 256, 0, stream>>>(x_v, nV, llw(0, 1), nullptr, 0, t_v,
                                                            lrw(0, 0), nullptr, 0, x_v);
    agg_kernel<<<(nV + 3) / 4, 256, 0, stream>>>(t_c, rp_v, adj_v, llb(0, 0), x_v, nV);
    agg_kernel<<<(nC + 3) / 4, 256, 0, stream>>>(t_v, rp_c, adj_c, llb(0, 1), x_c, nC);

    // ---- layer 1 (final): only new_v reaches the output ----
    gemm64_kernel<false><<<(nC + 63) / 64, 256, 0, stream>>>(x_c, nC, llw(1, 0), nullptr, 0, t_c,
                                                             nullptr, nullptr, 0, nullptr);
    gemm64_kernel<false><<<(nV + 63) / 64, 256, 0, stream>>>(x_v, nV, lrw(1, 0), nullptr, 0, (float*)d_out,
                                                             nullptr, nullptr, 0, nullptr);
    agg_kernel<<<(nV + 3) / 4, 256, 0, stream>>>(t_c, rp_v, adj_v, llb(1, 0), (float*)d_out, nV);
}

// Round 2
// 820.689 us; speedup vs baseline: 1.1796x; 1.1796x over previous
//
#include <hip/hip_runtime.h>

#define EMB 64

// ---------------------------------------------------------------------------
// Round 2: replace the naive CSR scatter (254MB of partial-line HBM writes,
// 253us) with a two-phase binned build where every write region is owned by
// a single workgroup (single XCD L2 -> lines fill before eviction):
//   bin_edges: chunk-per-wg LDS histogram over ~391 node-range buckets,
//              reserve runs via one atomicAdd per (wg,bucket), write {other,node}
//              pairs into this wg's contiguous runs. Bucket bases = rp[b<<sh].
//   regroup:   wg-per-bucket, LDS per-node rank counters, write final adj into
//              the bucket's contiguous region.
// tmp arrays alias t_c/t_v (only used later in the pipeline).
// ---------------------------------------------------------------------------

__global__ __launch_bounds__(256) void zero_int_kernel(int* __restrict__ p, int n) {
    int i = blockIdx.x * 256 + threadIdx.x;
    if (i < n) p[i] = 0;
}

__global__ __launch_bounds__(256) void hist_kernel(const int* __restrict__ src, const int* __restrict__ dst,
                                                   int E, int* __restrict__ cnt_c, int* __restrict__ cnt_v) {
    int i = blockIdx.x * 256 + threadIdx.x;
    if (i < E) {
        atomicAdd(&cnt_v[dst[i]], 1);
        atomicAdd(&cnt_c[src[i]], 1);
    }
}

// per-block (2048 elems) exclusive scan; emits per-block totals
__global__ __launch_bounds__(256) void scan_blocks_kernel(const int* __restrict__ cnt, int* __restrict__ excl,
                                                          int* __restrict__ bsums, int n) {
    __shared__ int tot[256];
    int t = threadIdx.x;
    int base = blockIdx.x * 2048 + t * 8;
    int v[8];
    int s = 0;
#pragma unroll
    for (int i = 0; i < 8; ++i) { v[i] = (base + i < n) ? cnt[base + i] : 0; s += v[i]; }
    tot[t] = s;
    __syncthreads();
    for (int off = 1; off < 256; off <<= 1) {
        int x = (t >= off) ? tot[t - off] : 0;
        __syncthreads();
        tot[t] += x;
        __syncthreads();
    }
    int run = (t > 0) ? tot[t - 1] : 0;
#pragma unroll
    for (int i = 0; i < 8; ++i) {
        if (base + i < n) excl[base + i] = run;
        run += v[i];
    }
    if (t == 255) bsums[blockIdx.x] = tot[255];
}

// single-block exclusive scan of up to 256 block totals (in place)
__global__ __launch_bounds__(256) void scan_small_kernel(int* __restrict__ data, int n) {
    __shared__ int tot[256];
    int t = threadIdx.x;
    tot[t] = (t < n) ? data[t] : 0;
    __syncthreads();
    for (int off = 1; off < 256; off <<= 1) {
        int x = (t >= off) ? tot[t - off] : 0;
        __syncthreads();
        tot[t] += x;
        __syncthreads();
    }
    if (t < n) data[t] = (t > 0) ? tot[t - 1] : 0;
}

__global__ __launch_bounds__(256) void scan_add_kernel(int* __restrict__ rowptr, const int* __restrict__ bsums,
                                                       int n, int total) {
    int i = blockIdx.x * 256 + threadIdx.x;
    if (i < n) rowptr[i] += bsums[i >> 11];
    else if (i == n) rowptr[i] = total;
}

// gcur[b] = rp[min(b<<sh, n)]
__global__ __launch_bounds__(256) void init_gcur_kernel(const int* __restrict__ rp_c, const int* __restrict__ rp_v,
                                                        int* __restrict__ gcur_c, int* __restrict__ gcur_v,
                                                        int shc, int shv, int NBC, int NBV, int nC, int nV) {
    int i = blockIdx.x * 256 + threadIdx.x;
    if (i < NBC) gcur_c[i] = rp_c[min(i << shc, nC)];
    if (i < NBV) gcur_v[i] = rp_v[min(i << shv, nV)];
}

// Phase 1: per-4096-edge-chunk LDS binning into node-range buckets; each wg
// reserves contiguous runs in tmp_* and writes only into its own runs.
#define CH 4096
__global__ __launch_bounds__(256) void bin_edges_kernel(
    const int* __restrict__ src, const int* __restrict__ dst, int E,
    int* __restrict__ gcur_c, int* __restrict__ gcur_v,
    uint2* __restrict__ tmp_c, uint2* __restrict__ tmp_v,
    int shc, int shv, int NBC, int NBV)
{
    __shared__ int hc[512], hv[512];   // per-chunk bucket counts -> then cursors
    int t = threadIdx.x;
    int base = blockIdx.x * CH;
    int n = min(CH, E - base);

    for (int i = t; i < NBC; i += 256) hc[i] = 0;
    for (int i = t; i < NBV; i += 256) hv[i] = 0;
    __syncthreads();

    int ss[16], dd[16];
#pragma unroll
    for (int q = 0; q < 16; ++q) {
        int li = t + q * 256;
        bool ok = li < n;
        ss[q] = ok ? src[base + li] : -1;
        dd[q] = ok ? dst[base + li] : -1;
        if (ok) {
            atomicAdd(&hc[ss[q] >> shc], 1);
            atomicAdd(&hv[dd[q] >> shv], 1);
        }
    }
    __syncthreads();

    // reserve global runs (one atomic per non-empty bucket per wg)
    for (int i = t; i < NBC; i += 256) {
        int c = hc[i];
        hc[i] = c ? atomicAdd(&gcur_c[i], c) : 0;
    }
    for (int i = t; i < NBV; i += 256) {
        int c = hv[i];
        hv[i] = c ? atomicAdd(&gcur_v[i], c) : 0;
    }
    __syncthreads();

#pragma unroll
    for (int q = 0; q < 16; ++q) {
        int li = t + q * 256;
        if (li < n) {
            int s = ss[q], d = dd[q];
            int pc = atomicAdd(&hc[s >> shc], 1);
            tmp_c[pc] = make_uint2((unsigned)d, (unsigned)s);
            int pv = atomicAdd(&hv[d >> shv], 1);
            tmp_v[pv] = make_uint2((unsigned)s, (unsigned)d);
        }
    }
}

// Phase 2: wg-per-bucket; LDS rank counters over the bucket's node range;
// final adj writes stay inside the bucket's contiguous region.
__global__ __launch_bounds__(256) void regroup_kernel(
    const uint2* __restrict__ tmp, const int* __restrict__ rp,
    int* __restrict__ adj, int n_nodes, int sh)
{
    __shared__ int cnt[1024];
    int width = 1 << sh;
    int b = blockIdx.x;
    int node0 = b << sh;
    int node1 = min(node0 + width, n_nodes);
    for (int i = threadIdx.x; i < width; i += 256) cnt[i] = 0;
    __syncthreads();
    int beg = rp[node0], end = rp[node1];
    for (int e = beg + threadIdx.x; e < end; e += 256) {
        uint2 p = tmp[e];
        int d = (int)p.y;
        int r = atomicAdd(&cnt[d - node0], 1);
        adj[rp[d] + r] = (int)p.x;
    }
}

// h = relu(((x+shift)*scale) @ W1 + b1); one wave per row, lane = out column
__global__ __launch_bounds__(256) void embed1_kernel(
    const float* __restrict__ x, const float* __restrict__ shift, const float* __restrict__ scale,
    const float* __restrict__ w1, const float* __restrict__ b1,
    float* __restrict__ h, int n, int nf)
{
    __shared__ float w1s[19 * EMB];
    __shared__ float ssc[2 * 19];
    int tid = threadIdx.x;
    for (int i = tid; i < nf * EMB; i += 256) w1s[i] = w1[i];
    if (tid < nf) { ssc[tid] = shift[tid]; ssc[19 + tid] = scale[tid]; }
    __syncthreads();
    int lane = tid & 63;
    int row = blockIdx.x * 4 + (tid >> 6);
    if (row >= n) return;
    float acc = b1[lane];
    for (int k = 0; k < nf; ++k) {
        float xv = (x[(long)row * nf + k] + ssc[k]) * ssc[19 + k];
        acc = fmaf(xv, w1s[k * EMB + lane], acc);
    }
    h[(long)row * EMB + lane] = fmaxf(acc, 0.f);
}

// C1 = act(X@W1 [+B1]); optionally C2 = act(X@W2 [+B2]) sharing the X tile.
// C2 may alias X (tile fully staged to LDS before any store; blocks own
// disjoint 64-row ranges).
template <bool HAS2>
__global__ __launch_bounds__(256) void gemm64_kernel(
    const float* __restrict__ X, int n,
    const float* __restrict__ W1, const float* __restrict__ B1, int relu1, float* __restrict__ C1,
    const float* __restrict__ W2, const float* __restrict__ B2, int relu2, float* __restrict__ C2)
{
    __shared__ float xs[EMB * 68];            // transposed tile: xs[k*68 + r]
    __shared__ float w1s[EMB * EMB];
    __shared__ float w2s[HAS2 ? (EMB * EMB) : 4];

    int t = threadIdx.x;
    {
        int r = t >> 2;
        int cs = (t & 3) * 16;
        long gr = (long)blockIdx.x * 64 + r;
        float4 v[4];
        if (gr < n) {
            const float4* sp = (const float4*)(X + gr * EMB + cs);
#pragma unroll
            for (int q = 0; q < 4; ++q) v[q] = sp[q];
        } else {
            float4 z = make_float4(0.f, 0.f, 0.f, 0.f);
#pragma unroll
            for (int q = 0; q < 4; ++q) v[q] = z;
        }
#pragma unroll
        for (int q = 0; q < 4; ++q) {
            xs[(cs + q * 4 + 0) * 68 + r] = v[q].x;
            xs[(cs + q * 4 + 1) * 68 + r] = v[q].y;
            xs[(cs + q * 4 + 2) * 68 + r] = v[q].z;
            xs[(cs + q * 4 + 3) * 68 + r] = v[q].w;
        }
        const float4* wg1 = (const float4*)W1;
        float4* wl1 = (float4*)w1s;
#pragma unroll
        for (int q = 0; q < 4; ++q) wl1[t + q * 256] = wg1[t + q * 256];
        if (HAS2) {
            const float4* wg2 = (const float4*)W2;
            float4* wl2 = (float4*)w2s;
#pragma unroll
            for (int q = 0; q < 4; ++q) wl2[t + q * 256] = wg2[t + q * 256];
        }
    }
    __syncthreads();

    int r0 = (t >> 4) * 4;
    int c0 = (t & 15) * 4;
    float acc1[4][4] = {{0.f}};
    float acc2[4][4] = {{0.f}};
#pragma unroll 8
    for (int k = 0; k < EMB; ++k) {
        float4 xv = *(const float4*)&xs[k * 68 + r0];
        float4 wv = *(const float4*)&w1s[k * EMB + c0];
        float xa[4] = {xv.x, xv.y, xv.z, xv.w};
        float wa[4] = {wv.x, wv.y, wv.z, wv.w};
#pragma unroll
        for (int i = 0; i < 4; ++i)
#pragma unroll
            for (int j = 0; j < 4; ++j)
                acc1[i][j] = fmaf(xa[i], wa[j], acc1[i][j]);
        if (HAS2) {
            float4 w2v = *(const float4*)&w2s[k * EMB + c0];
            float wb[4] = {w2v.x, w2v.y, w2v.z, w2v.w};
#pragma unroll
            for (int i = 0; i < 4; ++i)
#pragma unroll
                for (int j = 0; j < 4; ++j)
                    acc2[i][j] = fmaf(xa[i], wb[j], acc2[i][j]);
        }
    }

    float4 b1v = make_float4(0.f, 0.f, 0.f, 0.f);
    if (B1) b1v = *(const float4*)&B1[c0];
#pragma unroll
    for (int i = 0; i < 4; ++i) {
        long gr = (long)blockIdx.x * 64 + r0 + i;
        if (gr < n) {
            float o0 = acc1[i][0] + b1v.x;
            float o1 = acc1[i][1] + b1v.y;
            float o2 = acc1[i][2] + b1v.z;
            float o3 = acc1[i][3] + b1v.w;
            if (relu1) { o0 = fmaxf(o0, 0.f); o1 = fmaxf(o1, 0.f); o2 = fmaxf(o2, 0.f); o3 = fmaxf(o3, 0.f); }
            *(float4*)&C1[gr * EMB + c0] = make_float4(o0, o1, o2, o3);
        }
    }
    if (HAS2) {
        float4 b2v = make_float4(0.f, 0.f, 0.f, 0.f);
        if (B2) b2v = *(const float4*)&B2[c0];
#pragma unroll
        for (int i = 0; i < 4; ++i) {
            long gr = (long)blockIdx.x * 64 + r0 + i;
            if (gr < n) {
                float o0 = acc2[i][0] + b2v.x;
                float o1 = acc2[i][1] + b2v.y;
                float o2 = acc2[i][2] + b2v.z;
                float o3 = acc2[i][3] + b2v.w;
                if (relu2) { o0 = fmaxf(o0, 0.f); o1 = fmaxf(o1, 0.f); o2 = fmaxf(o2, 0.f); o3 = fmaxf(o3, 0.f); }
                *(float4*)&C2[gr * EMB + c0] = make_float4(o0, o1, o2, o3);
            }
        }
    }
}

// out[node] = relu(mean_{nbr in CSR} t_src[nbr] + bias + out[node])
// wave per node; lane = feature; neighbor rows are coalesced 256B reads.
__global__ __launch_bounds__(256) void agg_kernel(
    const float* __restrict__ t_src, const int* __restrict__ rowptr, const int* __restrict__ adj,
    const float* __restrict__ bias, float* __restrict__ out, int n_dst)
{
    int lane = threadIdx.x & 63;
    int node = blockIdx.x * 4 + (threadIdx.x >> 6);
    if (node >= n_dst) return;
    int beg = rowptr[node];
    int end = rowptr[node + 1];
    float acc = 0.f;
    int e = beg;
    for (; e + 4 <= end; e += 4) {
        int n0 = adj[e + 0];
        int n1 = adj[e + 1];
        int n2 = adj[e + 2];
        int n3 = adj[e + 3];
        float v0 = t_src[n0 * EMB + lane];
        float v1 = t_src[n1 * EMB + lane];
        float v2 = t_src[n2 * EMB + lane];
        float v3 = t_src[n3 * EMB + lane];
        acc += (v0 + v1) + (v2 + v3);
    }
    for (; e < end; ++e) acc += t_src[adj[e] * EMB + lane];
    int cnt = end - beg;
    float mean = acc / (float)(cnt > 0 ? cnt : 1);
    float val = mean + bias[lane] + out[(long)node * EMB + lane];
    out[(long)node * EMB + lane] = fmaxf(val, 0.f);
}

extern "C" void kernel_launch(void* const* d_in, const int* in_sizes, int n_in,
                              void* d_out, int out_size, void* d_ws, size_t ws_size,
                              hipStream_t stream) {
    const float* cons_x     = (const float*)d_in[0];
    const float* var_x      = (const float*)d_in[1];
    const int*   eidx       = (const int*)d_in[3];
    const float* cons_shift = (const float*)d_in[4];
    const float* cons_scale = (const float*)d_in[5];
    const float* cons_w1    = (const float*)d_in[6];
    const float* cons_b1    = (const float*)d_in[7];
    const float* cons_w2    = (const float*)d_in[8];
    const float* cons_b2    = (const float*)d_in[9];
    const float* var_shift  = (const float*)d_in[10];
    const float* var_scale  = (const float*)d_in[11];
    const float* var_w1     = (const float*)d_in[12];
    const float* var_b1     = (const float*)d_in[13];
    const float* var_w2     = (const float*)d_in[14];
    const float* var_b2     = (const float*)d_in[15];
    const float* ll_w       = (const float*)d_in[18];
    const float* ll_b       = (const float*)d_in[19];
    const float* lr_w       = (const float*)d_in[20];

    const int nC = in_sizes[0] / 5;
    const int nV = in_sizes[1] / 19;
    const int E  = in_sizes[3] / 2;
    const int* src = eidx;       // constraint ids
    const int* dst = eidx + E;   // variable ids

    // bucket shifts such that bucket counts <= 512 (LDS arrays)
    int shc = 0; while ((nC >> shc) >= 512) ++shc;
    int shv = 0; while ((nV >> shv) >= 512) ++shv;
    const int NBC = (nC + (1 << shc) - 1) >> shc;
    const int NBV = (nV + (1 << shv) - 1) >> shv;

    char* w = (char*)d_ws;
    auto alloc = [&](size_t bytes) {
        char* p = w;
        w += (bytes + 255) & ~(size_t)255;
        return p;
    };
    float* x_c = (float*)alloc((size_t)nC * EMB * 4);
    float* x_v = (float*)alloc((size_t)nV * EMB * 4);
    float* t_c = (float*)alloc((size_t)nC * EMB * 4);   // aliases tmp_c during CSR build
    float* t_v = (float*)alloc((size_t)nV * EMB * 4);   // aliases tmp_v during CSR build
    uint2* tmp_c = (uint2*)t_c;   // E*8 = 16MB <= nC*EMB*4 = 25.6MB
    uint2* tmp_v = (uint2*)t_v;   // 16MB <= 51.2MB
    int* rp_v  = (int*)alloc((size_t)(nV + 1) * 4);
    int* rp_c  = (int*)alloc((size_t)(nC + 1) * 4);
    int* cnts  = (int*)alloc((size_t)(nV + nC) * 4);  // cnt_v, cnt_c
    int* cnt_v = cnts;
    int* cnt_c = cnts + nV;
    int* adj_v = (int*)alloc((size_t)E * 4);
    int* adj_c = (int*)alloc((size_t)E * 4);
    int* bs_v  = (int*)alloc(256 * 4);
    int* bs_c  = (int*)alloc(256 * 4);
    int* gcur_c = (int*)alloc(1024 * 4);
    int* gcur_v = (int*)alloc(1024 * 4);

    auto llw = [&](int l, int d) { return ll_w + (size_t)(l * 2 + d) * EMB * EMB; };
    auto lrw = [&](int l, int d) { return lr_w + (size_t)(l * 2 + d) * EMB * EMB; };
    auto llb = [&](int l, int d) { return ll_b + (size_t)(l * 2 + d) * EMB; };

    // ---- CSR build ----
    int nz = nV + nC;
    zero_int_kernel<<<(nz + 255) / 256, 256, 0, stream>>>(cnts, nz);
    hist_kernel<<<(E + 255) / 256, 256, 0, stream>>>(src, dst, E, cnt_c, cnt_v);
    int Bv = (nV + 2047) / 2048, Bc = (nC + 2047) / 2048;
    scan_blocks_kernel<<<Bv, 256, 0, stream>>>(cnt_v, rp_v, bs_v, nV);
    scan_small_kernel<<<1, 256, 0, stream>>>(bs_v, Bv);
    scan_add_kernel<<<(nV + 1 + 255) / 256, 256, 0, stream>>>(rp_v, bs_v, nV, E);
    scan_blocks_kernel<<<Bc, 256, 0, stream>>>(cnt_c, rp_c, bs_c, nC);
    scan_small_kernel<<<1, 256, 0, stream>>>(bs_c, Bc);
    scan_add_kernel<<<(nC + 1 + 255) / 256, 256, 0, stream>>>(rp_c, bs_c, nC, E);
    init_gcur_kernel<<<(max(NBC, NBV) + 255) / 256, 256, 0, stream>>>(rp_c, rp_v, gcur_c, gcur_v,
                                                                      shc, shv, NBC, NBV, nC, nV);
    bin_edges_kernel<<<(E + CH - 1) / CH, 256, 0, stream>>>(src, dst, E, gcur_c, gcur_v,
                                                            tmp_c, tmp_v, shc, shv, NBC, NBV);
    regroup_kernel<<<NBV, 256, 0, stream>>>(tmp_v, rp_v, adj_v, nV, shv);
    regroup_kernel<<<NBC, 256, 0, stream>>>(tmp_c, rp_c, adj_c, nC, shc);

    // ---- node embeddings (t_c/t_v reused as hidden now that tmp is consumed) ----
    embed1_kernel<<<(nC + 3) / 4, 256, 0, stream>>>(cons_x, cons_shift, cons_scale, cons_w1, cons_b1, t_c, nC, 5);
    gemm64_kernel<false><<<(nC + 63) / 64, 256, 0, stream>>>(t_c, nC, cons_w2, cons_b2, 1, x_c,
                                                             nullptr, nullptr, 0, nullptr);
    embed1_kernel<<<(nV + 3) / 4, 256, 0, stream>>>(var_x, var_shift, var_scale, var_w1, var_b1, t_v, nV, 19);
    gemm64_kernel<false><<<(nV + 63) / 64, 256, 0, stream>>>(t_v, nV, var_w2, var_b2, 1, x_v,
                                                             nullptr, nullptr, 0, nullptr);

    // ---- layer 0 (u-terms written in place into x_c / x_v) ----
    gemm64_kernel<true><<<(nC + 63) / 64, 256, 0, stream>>>(x_c, nC, llw(0, 0), nullptr, 0, t_c,
                                                            lrw(0, 1), nullptr, 0, x_c);
    gemm64_kernel<true><<<(nV + 63) / 64, 256, 0, stream>>>(x_v, nV, llw(0, 1), nullptr, 0, t_v,
                                                            lrw(0, 0), nullptr, 0, x_v);
    agg_kernel<<<(nV + 3) / 4, 256, 0, stream>>>(t_c, rp_v, adj_v, llb(0, 0), x_v, nV);
    agg_kernel<<<(nC + 3) / 4, 256, 0, stream>>>(t_v, rp_c, adj_c, llb(0, 1), x_c, nC);

    // ---- layer 1 (final): only new_v reaches the output ----
    gemm64_kernel<false><<<(nC + 63) / 64, 256, 0, stream>>>(x_c, nC, llw(1, 0), nullptr, 0, t_c,
                                                             nullptr, nullptr, 0, nullptr);
    gemm64_kernel<false><<<(nV + 63) / 64, 256, 0, stream>>>(x_v, nV, lrw(1, 0), nullptr, 0, (float*)d_out,
                                                             nullptr, nullptr, 0, nullptr);
    agg_kernel<<<(nV + 3) / 4, 256, 0, stream>>>(t_c, rp_v, adj_v, llb(1, 0), (float*)d_out, nV);
}

// Round 3
// 670.058 us; speedup vs baseline: 1.4448x; 1.2248x over previous
//
#include <hip/hip_runtime.h>

#define EMB 64
#define CH 4096

// ---------------------------------------------------------------------------
// Round 3: kill the per-node global-atomic histogram (124.8MB of memory-side
// line dirtying, 155us). The binned CSR build now derives everything:
//   bucket_hist: per-chunk LDS histogram over <=512 node-range BUCKETS, one
//                global atomicAdd per (wg,bucket) -> ~380k atomics to ~780
//                hot counters (L2-resident), writes <1MB.
//   scan_buckets: single block scans bucket counts -> bucket bases.
//   bin_edges:   per-chunk LDS binning; reserves contiguous runs per
//                (wg,bucket) at bucket_base + cursor; writes {other,node}.
//   regroup2:    wg-per-bucket; LDS per-node hist + exclusive scan writes
//                rp[] (contiguous), then ranks edges and writes adj[] inside
//                the bucket's contiguous region. rowptr is a BY-PRODUCT; the
//                old hist + node-scan kernels are deleted.
// tmp pair arrays alias t_c/t_v (used only later in the pipeline).
// ---------------------------------------------------------------------------

__global__ __launch_bounds__(256) void zero_int_kernel(int* __restrict__ p, int n) {
    int i = blockIdx.x * 256 + threadIdx.x;
    if (i < n) p[i] = 0;
}

__global__ __launch_bounds__(256) void bucket_hist_kernel(
    const int* __restrict__ src, const int* __restrict__ dst, int E,
    int* __restrict__ bkt_cnt_c, int* __restrict__ bkt_cnt_v,
    int shc, int shv, int NBC, int NBV)
{
    __shared__ int hc[512], hv[512];
    int t = threadIdx.x;
    int base = blockIdx.x * CH;
    int n = min(CH, E - base);
    for (int i = t; i < NBC; i += 256) hc[i] = 0;
    for (int i = t; i < NBV; i += 256) hv[i] = 0;
    __syncthreads();
    for (int li = t; li < n; li += 256) {
        atomicAdd(&hc[src[base + li] >> shc], 1);
        atomicAdd(&hv[dst[base + li] >> shv], 1);
    }
    __syncthreads();
    for (int i = t; i < NBC; i += 256) { int c = hc[i]; if (c) atomicAdd(&bkt_cnt_c[i], c); }
    for (int i = t; i < NBV; i += 256) { int c = hv[i]; if (c) atomicAdd(&bkt_cnt_v[i], c); }
}

// one block: exclusive-scan both bucket-count arrays in place; data[n] = E
__global__ __launch_bounds__(256) void scan_buckets_kernel(
    int* __restrict__ bc, int nbc, int* __restrict__ bv, int nbv, int E)
{
    __shared__ int sc[256];
    int t = threadIdx.x;
    {
        int v0 = (2 * t < nbc) ? bc[2 * t] : 0;
        int v1 = (2 * t + 1 < nbc) ? bc[2 * t + 1] : 0;
        sc[t] = v0 + v1;
        __syncthreads();
        for (int off = 1; off < 256; off <<= 1) {
            int x = (t >= off) ? sc[t - off] : 0;
            __syncthreads();
            sc[t] += x;
            __syncthreads();
        }
        int ex = (t > 0) ? sc[t - 1] : 0;
        if (2 * t < nbc) bc[2 * t] = ex;
        if (2 * t + 1 < nbc) bc[2 * t + 1] = ex + v0;
        if (t == 0) bc[nbc] = E;
        __syncthreads();
    }
    {
        int v0 = (2 * t < nbv) ? bv[2 * t] : 0;
        int v1 = (2 * t + 1 < nbv) ? bv[2 * t + 1] : 0;
        sc[t] = v0 + v1;
        __syncthreads();
        for (int off = 1; off < 256; off <<= 1) {
            int x = (t >= off) ? sc[t - off] : 0;
            __syncthreads();
            sc[t] += x;
            __syncthreads();
        }
        int ex = (t > 0) ? sc[t - 1] : 0;
        if (2 * t < nbv) bv[2 * t] = ex;
        if (2 * t + 1 < nbv) bv[2 * t + 1] = ex + v0;
        if (t == 0) bv[nbv] = E;
    }
}

// Phase 1: per-chunk LDS binning; each wg reserves contiguous runs in tmp_*
// (at bucket_base + shared cursor) and writes only into its own runs.
__global__ __launch_bounds__(256) void bin_edges_kernel(
    const int* __restrict__ src, const int* __restrict__ dst, int E,
    const int* __restrict__ bb_c, const int* __restrict__ bb_v,
    int* __restrict__ gcur_c, int* __restrict__ gcur_v,
    uint2* __restrict__ tmp_c, uint2* __restrict__ tmp_v,
    int shc, int shv, int NBC, int NBV)
{
    __shared__ int hc[512], hv[512];
    int t = threadIdx.x;
    int base = blockIdx.x * CH;
    int n = min(CH, E - base);

    for (int i = t; i < NBC; i += 256) hc[i] = 0;
    for (int i = t; i < NBV; i += 256) hv[i] = 0;
    __syncthreads();

    int ss[16], dd[16];
#pragma unroll
    for (int q = 0; q < 16; ++q) {
        int li = t + q * 256;
        bool ok = li < n;
        ss[q] = ok ? src[base + li] : -1;
        dd[q] = ok ? dst[base + li] : -1;
        if (ok) {
            atomicAdd(&hc[ss[q] >> shc], 1);
            atomicAdd(&hv[dd[q] >> shv], 1);
        }
    }
    __syncthreads();

    for (int i = t; i < NBC; i += 256) {
        int c = hc[i];
        hc[i] = c ? (bb_c[i] + atomicAdd(&gcur_c[i], c)) : 0;
    }
    for (int i = t; i < NBV; i += 256) {
        int c = hv[i];
        hv[i] = c ? (bb_v[i] + atomicAdd(&gcur_v[i], c)) : 0;
    }
    __syncthreads();

#pragma unroll
    for (int q = 0; q < 16; ++q) {
        int li = t + q * 256;
        if (li < n) {
            int s = ss[q], d = dd[q];
            int pc = atomicAdd(&hc[s >> shc], 1);
            tmp_c[pc] = make_uint2((unsigned)d, (unsigned)s);
            int pv = atomicAdd(&hv[d >> shv], 1);
            tmp_v[pv] = make_uint2((unsigned)s, (unsigned)d);
        }
    }
}

// Phase 2: wg-per-bucket. Pass 1: LDS per-node hist -> exclusive scan ->
// write rp (contiguous). Pass 2: rank + write adj inside bucket region.
__global__ __launch_bounds__(256) void regroup2_kernel(
    const uint2* __restrict__ tmp, const int* __restrict__ bb,
    int* __restrict__ rp, int* __restrict__ adj, int n_nodes, int sh, int E, int nb)
{
    __shared__ int cnt[512];
    __shared__ int offs[512];
    __shared__ int sc[256];
    int t = threadIdx.x;
    int b = blockIdx.x;
    int node0 = b << sh;
    int node1 = min(node0 + (1 << sh), n_nodes);
    int nn = node1 - node0;
    for (int i = t; i < nn; i += 256) cnt[i] = 0;
    __syncthreads();
    int beg = bb[b], end = bb[b + 1];
    for (int e = beg + t; e < end; e += 256)
        atomicAdd(&cnt[(int)tmp[e].y - node0], 1);
    __syncthreads();
    // exclusive scan cnt[0..nn) -> offs (2 elems/thread)
    int v0 = (2 * t < nn) ? cnt[2 * t] : 0;
    int v1 = (2 * t + 1 < nn) ? cnt[2 * t + 1] : 0;
    sc[t] = v0 + v1;
    __syncthreads();
    for (int off = 1; off < 256; off <<= 1) {
        int x = (t >= off) ? sc[t - off] : 0;
        __syncthreads();
        sc[t] += x;
        __syncthreads();
    }
    int ex = (t > 0) ? sc[t - 1] : 0;
    if (2 * t < nn) offs[2 * t] = ex;
    if (2 * t + 1 < nn) offs[2 * t + 1] = ex + v0;
    __syncthreads();
    for (int i = t; i < nn; i += 256) {
        rp[node0 + i] = beg + offs[i];
        cnt[i] = 0;  // reuse as rank cursor
    }
    if (b == nb - 1 && t == 0) rp[n_nodes] = E;
    __syncthreads();
    for (int e = beg + t; e < end; e += 256) {
        uint2 p = tmp[e];
        int d = (int)p.y - node0;
        int r = atomicAdd(&cnt[d], 1);
        adj[beg + offs[d] + r] = (int)p.x;
    }
}

// h = relu(((x+shift)*scale) @ W1 + b1); one wave per row, lane = out column
__global__ __launch_bounds__(256) void embed1_kernel(
    const float* __restrict__ x, const float* __restrict__ shift, const float* __restrict__ scale,
    const float* __restrict__ w1, const float* __restrict__ b1,
    float* __restrict__ h, int n, int nf)
{
    __shared__ float w1s[19 * EMB];
    __shared__ float ssc[2 * 19];
    int tid = threadIdx.x;
    for (int i = tid; i < nf * EMB; i += 256) w1s[i] = w1[i];
    if (tid < nf) { ssc[tid] = shift[tid]; ssc[19 + tid] = scale[tid]; }
    __syncthreads();
    int lane = tid & 63;
    int row = blockIdx.x * 4 + (tid >> 6);
    if (row >= n) return;
    float acc = b1[lane];
    for (int k = 0; k < nf; ++k) {
        float xv = (x[(long)row * nf + k] + ssc[k]) * ssc[19 + k];
        acc = fmaf(xv, w1s[k * EMB + lane], acc);
    }
    h[(long)row * EMB + lane] = fmaxf(acc, 0.f);
}

// C1 = act(X@W1 [+B1]); optionally C2 = act(X@W2 [+B2]) sharing the X tile.
// C2 may alias X (tile fully staged to LDS before any store; blocks own
// disjoint 64-row ranges).
template <bool HAS2>
__global__ __launch_bounds__(256) void gemm64_kernel(
    const float* __restrict__ X, int n,
    const float* __restrict__ W1, const float* __restrict__ B1, int relu1, float* __restrict__ C1,
    const float* __restrict__ W2, const float* __restrict__ B2, int relu2, float* __restrict__ C2)
{
    __shared__ float xs[EMB * 68];            // transposed tile: xs[k*68 + r]
    __shared__ float w1s[EMB * EMB];
    __shared__ float w2s[HAS2 ? (EMB * EMB) : 4];

    int t = threadIdx.x;
    {
        int r = t >> 2;
        int cs = (t & 3) * 16;
        long gr = (long)blockIdx.x * 64 + r;
        float4 v[4];
        if (gr < n) {
            const float4* sp = (const float4*)(X + gr * EMB + cs);
#pragma unroll
            for (int q = 0; q < 4; ++q) v[q] = sp[q];
        } else {
            float4 z = make_float4(0.f, 0.f, 0.f, 0.f);
#pragma unroll
            for (int q = 0; q < 4; ++q) v[q] = z;
        }
#pragma unroll
        for (int q = 0; q < 4; ++q) {
            xs[(cs + q * 4 + 0) * 68 + r] = v[q].x;
            xs[(cs + q * 4 + 1) * 68 + r] = v[q].y;
            xs[(cs + q * 4 + 2) * 68 + r] = v[q].z;
            xs[(cs + q * 4 + 3) * 68 + r] = v[q].w;
        }
        const float4* wg1 = (const float4*)W1;
        float4* wl1 = (float4*)w1s;
#pragma unroll
        for (int q = 0; q < 4; ++q) wl1[t + q * 256] = wg1[t + q * 256];
        if (HAS2) {
            const float4* wg2 = (const float4*)W2;
            float4* wl2 = (float4*)w2s;
#pragma unroll
            for (int q = 0; q < 4; ++q) wl2[t + q * 256] = wg2[t + q * 256];
        }
    }
    __syncthreads();

    int r0 = (t >> 4) * 4;
    int c0 = (t & 15) * 4;
    float acc1[4][4] = {{0.f}};
    float acc2[4][4] = {{0.f}};
#pragma unroll 8
    for (int k = 0; k < EMB; ++k) {
        float4 xv = *(const float4*)&xs[k * 68 + r0];
        float4 wv = *(const float4*)&w1s[k * EMB + c0];
        float xa[4] = {xv.x, xv.y, xv.z, xv.w};
        float wa[4] = {wv.x, wv.y, wv.z, wv.w};
#pragma unroll
        for (int i = 0; i < 4; ++i)
#pragma unroll
            for (int j = 0; j < 4; ++j)
                acc1[i][j] = fmaf(xa[i], wa[j], acc1[i][j]);
        if (HAS2) {
            float4 w2v = *(const float4*)&w2s[k * EMB + c0];
            float wb[4] = {w2v.x, w2v.y, w2v.z, w2v.w};
#pragma unroll
            for (int i = 0; i < 4; ++i)
#pragma unroll
                for (int j = 0; j < 4; ++j)
                    acc2[i][j] = fmaf(xa[i], wb[j], acc2[i][j]);
        }
    }

    float4 b1v = make_float4(0.f, 0.f, 0.f, 0.f);
    if (B1) b1v = *(const float4*)&B1[c0];
#pragma unroll
    for (int i = 0; i < 4; ++i) {
        long gr = (long)blockIdx.x * 64 + r0 + i;
        if (gr < n) {
            float o0 = acc1[i][0] + b1v.x;
            float o1 = acc1[i][1] + b1v.y;
            float o2 = acc1[i][2] + b1v.z;
            float o3 = acc1[i][3] + b1v.w;
            if (relu1) { o0 = fmaxf(o0, 0.f); o1 = fmaxf(o1, 0.f); o2 = fmaxf(o2, 0.f); o3 = fmaxf(o3, 0.f); }
            *(float4*)&C1[gr * EMB + c0] = make_float4(o0, o1, o2, o3);
        }
    }
    if (HAS2) {
        float4 b2v = make_float4(0.f, 0.f, 0.f, 0.f);
        if (B2) b2v = *(const float4*)&B2[c0];
#pragma unroll
        for (int i = 0; i < 4; ++i) {
            long gr = (long)blockIdx.x * 64 + r0 + i;
            if (gr < n) {
                float o0 = acc2[i][0] + b2v.x;
                float o1 = acc2[i][1] + b2v.y;
                float o2 = acc2[i][2] + b2v.z;
                float o3 = acc2[i][3] + b2v.w;
                if (relu2) { o0 = fmaxf(o0, 0.f); o1 = fmaxf(o1, 0.f); o2 = fmaxf(o2, 0.f); o3 = fmaxf(o3, 0.f); }
                *(float4*)&C2[gr * EMB + c0] = make_float4(o0, o1, o2, o3);
            }
        }
    }
}

// out[node] = relu(mean_{nbr in CSR} t_src[nbr] + bias + out[node])
// wave per node; lane = feature; neighbor rows are coalesced 256B reads.
__global__ __launch_bounds__(256) void agg_kernel(
    const float* __restrict__ t_src, const int* __restrict__ rowptr, const int* __restrict__ adj,
    const float* __restrict__ bias, float* __restrict__ out, int n_dst)
{
    int lane = threadIdx.x & 63;
    int node = blockIdx.x * 4 + (threadIdx.x >> 6);
    if (node >= n_dst) return;
    int beg = rowptr[node];
    int end = rowptr[node + 1];
    float acc = 0.f;
    int e = beg;
    for (; e + 4 <= end; e += 4) {
        int n0 = adj[e + 0];
        int n1 = adj[e + 1];
        int n2 = adj[e + 2];
        int n3 = adj[e + 3];
        float v0 = t_src[n0 * EMB + lane];
        float v1 = t_src[n1 * EMB + lane];
        float v2 = t_src[n2 * EMB + lane];
        float v3 = t_src[n3 * EMB + lane];
        acc += (v0 + v1) + (v2 + v3);
    }
    for (; e < end; ++e) acc += t_src[adj[e] * EMB + lane];
    int cnt = end - beg;
    float mean = acc / (float)(cnt > 0 ? cnt : 1);
    float val = mean + bias[lane] + out[(long)node * EMB + lane];
    out[(long)node * EMB + lane] = fmaxf(val, 0.f);
}

extern "C" void kernel_launch(void* const* d_in, const int* in_sizes, int n_in,
                              void* d_out, int out_size, void* d_ws, size_t ws_size,
                              hipStream_t stream) {
    const float* cons_x     = (const float*)d_in[0];
    const float* var_x      = (const float*)d_in[1];
    const int*   eidx       = (const int*)d_in[3];
    const float* cons_shift = (const float*)d_in[4];
    const float* cons_scale = (const float*)d_in[5];
    const float* cons_w1    = (const float*)d_in[6];
    const float* cons_b1    = (const float*)d_in[7];
    const float* cons_w2    = (const float*)d_in[8];
    const float* cons_b2    = (const float*)d_in[9];
    const float* var_shift  = (const float*)d_in[10];
    const float* var_scale  = (const float*)d_in[11];
    const float* var_w1     = (const float*)d_in[12];
    const float* var_b1     = (const float*)d_in[13];
    const float* var_w2     = (const float*)d_in[14];
    const float* var_b2     = (const float*)d_in[15];
    const float* ll_w       = (const float*)d_in[18];
    const float* ll_b       = (const float*)d_in[19];
    const float* lr_w       = (const float*)d_in[20];

    const int nC = in_sizes[0] / 5;
    const int nV = in_sizes[1] / 19;
    const int E  = in_sizes[3] / 2;
    const int* src = eidx;       // constraint ids
    const int* dst = eidx + E;   // variable ids

    // bucket shifts such that bucket node counts <= 512 (LDS arrays)
    int shc = 0; while ((nC >> shc) >= 512) ++shc;
    int shv = 0; while ((nV >> shv) >= 512) ++shv;
    const int NBC = (nC + (1 << shc) - 1) >> shc;
    const int NBV = (nV + (1 << shv) - 1) >> shv;

    char* w = (char*)d_ws;
    auto alloc = [&](size_t bytes) {
        char* p = w;
        w += (bytes + 255) & ~(size_t)255;
        return p;
    };
    float* x_c = (float*)alloc((size_t)nC * EMB * 4);
    float* x_v = (float*)alloc((size_t)nV * EMB * 4);
    float* t_c = (float*)alloc((size_t)nC * EMB * 4);   // aliases tmp_c during CSR build
    float* t_v = (float*)alloc((size_t)nV * EMB * 4);   // aliases tmp_v during CSR build
    uint2* tmp_c = (uint2*)t_c;   // E*8 = 16MB <= 25.6MB
    uint2* tmp_v = (uint2*)t_v;   // 16MB <= 51.2MB
    int* rp_v  = (int*)alloc((size_t)(nV + 1) * 4);
    int* rp_c  = (int*)alloc((size_t)(nC + 1) * 4);
    int* adj_v = (int*)alloc((size_t)E * 4);
    int* adj_c = (int*)alloc((size_t)E * 4);
    int* bkt   = (int*)alloc(4096 * 4);   // contiguous: bb_c, bb_v, gcur_c, gcur_v
    int* bb_c   = bkt;                    // NBC+1
    int* bb_v   = bkt + 1024;             // NBV+1
    int* gcur_c = bkt + 2048;             // NBC
    int* gcur_v = bkt + 3072;             // NBV

    auto llw = [&](int l, int d) { return ll_w + (size_t)(l * 2 + d) * EMB * EMB; };
    auto lrw = [&](int l, int d) { return lr_w + (size_t)(l * 2 + d) * EMB * EMB; };
    auto llb = [&](int l, int d) { return ll_b + (size_t)(l * 2 + d) * EMB; };

    // ---- CSR build (bucket-binned, no per-node global atomics) ----
    zero_int_kernel<<<16, 256, 0, stream>>>(bkt, 4096);
    bucket_hist_kernel<<<(E + CH - 1) / CH, 256, 0, stream>>>(src, dst, E, bb_c, bb_v, shc, shv, NBC, NBV);
    scan_buckets_kernel<<<1, 256, 0, stream>>>(bb_c, NBC, bb_v, NBV, E);
    bin_edges_kernel<<<(E + CH - 1) / CH, 256, 0, stream>>>(src, dst, E, bb_c, bb_v, gcur_c, gcur_v,
                                                            tmp_c, tmp_v, shc, shv, NBC, NBV);
    regroup2_kernel<<<NBV, 256, 0, stream>>>(tmp_v, bb_v, rp_v, adj_v, nV, shv, E, NBV);
    regroup2_kernel<<<NBC, 256, 0, stream>>>(tmp_c, bb_c, rp_c, adj_c, nC, shc, E, NBC);

    // ---- node embeddings (t_c/t_v reused as hidden now that tmp is consumed) ----
    embed1_kernel<<<(nC + 3) / 4, 256, 0, stream>>>(cons_x, cons_shift, cons_scale, cons_w1, cons_b1, t_c, nC, 5);
    gemm64_kernel<false><<<(nC + 63) / 64, 256, 0, stream>>>(t_c, nC, cons_w2, cons_b2, 1, x_c,
                                                             nullptr, nullptr, 0, nullptr);
    embed1_kernel<<<(nV + 3) / 4, 256, 0, stream>>>(var_x, var_shift, var_scale, var_w1, var_b1, t_v, nV, 19);
    gemm64_kernel<false><<<(nV + 63) / 64, 256, 0, stream>>>(t_v, nV, var_w2, var_b2, 1, x_v,
                                                             nullptr, nullptr, 0, nullptr);

    // ---- layer 0 (u-terms written in place into x_c / x_v) ----
    gemm64_kernel<true><<<(nC + 63) / 64, 256, 0, stream>>>(x_c, nC, llw(0, 0), nullptr, 0, t_c,
                                                            lrw(0, 1), nullptr, 0, x_c);
    gemm64_kernel<true><<<(nV + 63) / 64, 256, 0, stream>>>(x_v, nV, llw(0, 1), nullptr, 0, t_v,
                                                            lrw(0, 0), nullptr, 0, x_v);
    agg_kernel<<<(nV + 3) / 4, 256, 0, stream>>>(t_c, rp_v, adj_v, llb(0, 0), x_v, nV);
    agg_kernel<<<(nC + 3) / 4, 256, 0, stream>>>(t_v, rp_c, adj_c, llb(0, 1), x_c, nC);

    // ---- layer 1 (final): only new_v reaches the output ----
    gemm64_kernel<false><<<(nC + 63) / 64, 256, 0, stream>>>(x_c, nC, llw(1, 0), nullptr, 0, t_c,
                                                             nullptr, nullptr, 0, nullptr);
    gemm64_kernel<false><<<(nV + 63) / 64, 256, 0, stream>>>(x_v, nV, lrw(1, 0), nullptr, 0, (float*)d_out,
                                                             nullptr, nullptr, 0, nullptr);
    agg_kernel<<<(nV + 3) / 4, 256, 0, stream>>>(t_c, rp_v, adj_v, llb(1, 0), (float*)d_out, nV);
}

// Round 4
// 634.520 us; speedup vs baseline: 1.5257x; 1.0560x over previous
//
#include <hip/hip_runtime.h>

#define EMB 64
#define CH 4096

// ---------------------------------------------------------------------------
// Round 4: the 3 agg dispatches (105us each) are pure random-gather BW:
// 512MB payload/dispatch, 50% L2 hit, ~4.9TB/s effective. Only lever is
// bytes/row -> store the aggregation tables (t = x @ ll_w) in bf16:
//   - gather payload halves (256B -> 128B per row)
//   - bf16 tables (12.8/25.6MB) nearly fit aggregate L2 (32MB)
//   - accumulation stays fp32; u-term + bias + relu stay fp32
// agg_kernel: node per wave; lane = (feature pair, neighbor parity);
// 4B/lane/neighbor, 2 neighbors in flight + unroll 2; shfl_xor(32) reduce.
// bf16 tables alias the dead fp32 hidden buffers -> no extra workspace.
// ---------------------------------------------------------------------------

static __device__ __forceinline__ unsigned short f2bf(float x) {
    union { float f; unsigned u; } v; v.f = x;
    unsigned r = v.u + 0x7fffu + ((v.u >> 16) & 1u);   // RNE
    return (unsigned short)(r >> 16);
}
static __device__ __forceinline__ float bflo(unsigned w) {
    union { unsigned u; float f; } v; v.u = w << 16; return v.f;
}
static __device__ __forceinline__ float bfhi(unsigned w) {
    union { unsigned u; float f; } v; v.u = w & 0xffff0000u; return v.f;
}

__global__ __launch_bounds__(256) void zero_int_kernel(int* __restrict__ p, int n) {
    int i = blockIdx.x * 256 + threadIdx.x;
    if (i < n) p[i] = 0;
}

__global__ __launch_bounds__(256) void bucket_hist_kernel(
    const int* __restrict__ src, const int* __restrict__ dst, int E,
    int* __restrict__ bkt_cnt_c, int* __restrict__ bkt_cnt_v,
    int shc, int shv, int NBC, int NBV)
{
    __shared__ int hc[512], hv[512];
    int t = threadIdx.x;
    int base = blockIdx.x * CH;
    int n = min(CH, E - base);
    for (int i = t; i < NBC; i += 256) hc[i] = 0;
    for (int i = t; i < NBV; i += 256) hv[i] = 0;
    __syncthreads();
    for (int li = t; li < n; li += 256) {
        atomicAdd(&hc[src[base + li] >> shc], 1);
        atomicAdd(&hv[dst[base + li] >> shv], 1);
    }
    __syncthreads();
    for (int i = t; i < NBC; i += 256) { int c = hc[i]; if (c) atomicAdd(&bkt_cnt_c[i], c); }
    for (int i = t; i < NBV; i += 256) { int c = hv[i]; if (c) atomicAdd(&bkt_cnt_v[i], c); }
}

// one block: exclusive-scan both bucket-count arrays in place; data[n] = E
__global__ __launch_bounds__(256) void scan_buckets_kernel(
    int* __restrict__ bc, int nbc, int* __restrict__ bv, int nbv, int E)
{
    __shared__ int sc[256];
    int t = threadIdx.x;
    {
        int v0 = (2 * t < nbc) ? bc[2 * t] : 0;
        int v1 = (2 * t + 1 < nbc) ? bc[2 * t + 1] : 0;
        sc[t] = v0 + v1;
        __syncthreads();
        for (int off = 1; off < 256; off <<= 1) {
            int x = (t >= off) ? sc[t - off] : 0;
            __syncthreads();
            sc[t] += x;
            __syncthreads();
        }
        int ex = (t > 0) ? sc[t - 1] : 0;
        if (2 * t < nbc) bc[2 * t] = ex;
        if (2 * t + 1 < nbc) bc[2 * t + 1] = ex + v0;
        if (t == 0) bc[nbc] = E;
        __syncthreads();
    }
    {
        int v0 = (2 * t < nbv) ? bv[2 * t] : 0;
        int v1 = (2 * t + 1 < nbv) ? bv[2 * t + 1] : 0;
        sc[t] = v0 + v1;
        __syncthreads();
        for (int off = 1; off < 256; off <<= 1) {
            int x = (t >= off) ? sc[t - off] : 0;
            __syncthreads();
            sc[t] += x;
            __syncthreads();
        }
        int ex = (t > 0) ? sc[t - 1] : 0;
        if (2 * t < nbv) bv[2 * t] = ex;
        if (2 * t + 1 < nbv) bv[2 * t + 1] = ex + v0;
        if (t == 0) bv[nbv] = E;
    }
}

__global__ __launch_bounds__(256) void bin_edges_kernel(
    const int* __restrict__ src, const int* __restrict__ dst, int E,
    const int* __restrict__ bb_c, const int* __restrict__ bb_v,
    int* __restrict__ gcur_c, int* __restrict__ gcur_v,
    uint2* __restrict__ tmp_c, uint2* __restrict__ tmp_v,
    int shc, int shv, int NBC, int NBV)
{
    __shared__ int hc[512], hv[512];
    int t = threadIdx.x;
    int base = blockIdx.x * CH;
    int n = min(CH, E - base);

    for (int i = t; i < NBC; i += 256) hc[i] = 0;
    for (int i = t; i < NBV; i += 256) hv[i] = 0;
    __syncthreads();

    int ss[16], dd[16];
#pragma unroll
    for (int q = 0; q < 16; ++q) {
        int li = t + q * 256;
        bool ok = li < n;
        ss[q] = ok ? src[base + li] : -1;
        dd[q] = ok ? dst[base + li] : -1;
        if (ok) {
            atomicAdd(&hc[ss[q] >> shc], 1);
            atomicAdd(&hv[dd[q] >> shv], 1);
        }
    }
    __syncthreads();

    for (int i = t; i < NBC; i += 256) {
        int c = hc[i];
        hc[i] = c ? (bb_c[i] + atomicAdd(&gcur_c[i], c)) : 0;
    }
    for (int i = t; i < NBV; i += 256) {
        int c = hv[i];
        hv[i] = c ? (bb_v[i] + atomicAdd(&gcur_v[i], c)) : 0;
    }
    __syncthreads();

#pragma unroll
    for (int q = 0; q < 16; ++q) {
        int li = t + q * 256;
        if (li < n) {
            int s = ss[q], d = dd[q];
            int pc = atomicAdd(&hc[s >> shc], 1);
            tmp_c[pc] = make_uint2((unsigned)d, (unsigned)s);
            int pv = atomicAdd(&hv[d >> shv], 1);
            tmp_v[pv] = make_uint2((unsigned)s, (unsigned)d);
        }
    }
}

__global__ __launch_bounds__(256) void regroup2_kernel(
    const uint2* __restrict__ tmp, const int* __restrict__ bb,
    int* __restrict__ rp, int* __restrict__ adj, int n_nodes, int sh, int E, int nb)
{
    __shared__ int cnt[512];
    __shared__ int offs[512];
    __shared__ int sc[256];
    int t = threadIdx.x;
    int b = blockIdx.x;
    int node0 = b << sh;
    int node1 = min(node0 + (1 << sh), n_nodes);
    int nn = node1 - node0;
    for (int i = t; i < nn; i += 256) cnt[i] = 0;
    __syncthreads();
    int beg = bb[b], end = bb[b + 1];
    for (int e = beg + t; e < end; e += 256)
        atomicAdd(&cnt[(int)tmp[e].y - node0], 1);
    __syncthreads();
    int v0 = (2 * t < nn) ? cnt[2 * t] : 0;
    int v1 = (2 * t + 1 < nn) ? cnt[2 * t + 1] : 0;
    sc[t] = v0 + v1;
    __syncthreads();
    for (int off = 1; off < 256; off <<= 1) {
        int x = (t >= off) ? sc[t - off] : 0;
        __syncthreads();
        sc[t] += x;
        __syncthreads();
    }
    int ex = (t > 0) ? sc[t - 1] : 0;
    if (2 * t < nn) offs[2 * t] = ex;
    if (2 * t + 1 < nn) offs[2 * t + 1] = ex + v0;
    __syncthreads();
    for (int i = t; i < nn; i += 256) {
        rp[node0 + i] = beg + offs[i];
        cnt[i] = 0;
    }
    if (b == nb - 1 && t == 0) rp[n_nodes] = E;
    __syncthreads();
    for (int e = beg + t; e < end; e += 256) {
        uint2 p = tmp[e];
        int d = (int)p.y - node0;
        int r = atomicAdd(&cnt[d], 1);
        adj[beg + offs[d] + r] = (int)p.x;
    }
}

// h = relu(((x+shift)*scale) @ W1 + b1); one wave per row, lane = out column
__global__ __launch_bounds__(256) void embed1_kernel(
    const float* __restrict__ x, const float* __restrict__ shift, const float* __restrict__ scale,
    const float* __restrict__ w1, const float* __restrict__ b1,
    float* __restrict__ h, int n, int nf)
{
    __shared__ float w1s[19 * EMB];
    __shared__ float ssc[2 * 19];
    int tid = threadIdx.x;
    for (int i = tid; i < nf * EMB; i += 256) w1s[i] = w1[i];
    if (tid < nf) { ssc[tid] = shift[tid]; ssc[19 + tid] = scale[tid]; }
    __syncthreads();
    int lane = tid & 63;
    int row = blockIdx.x * 4 + (tid >> 6);
    if (row >= n) return;
    float acc = b1[lane];
    for (int k = 0; k < nf; ++k) {
        float xv = (x[(long)row * nf + k] + ssc[k]) * ssc[19 + k];
        acc = fmaf(xv, w1s[k * EMB + lane], acc);
    }
    h[(long)row * EMB + lane] = fmaxf(acc, 0.f);
}

// C1 = act(X@W1 [+B1]) (fp32 or bf16 out); optionally C2 = act(X@W2 [+B2])
// fp32, sharing the X tile. C2 may alias X.
template <bool HAS2, bool BF1>
__global__ __launch_bounds__(256) void gemm64_kernel(
    const float* __restrict__ X, int n,
    const float* __restrict__ W1, const float* __restrict__ B1, int relu1, void* __restrict__ C1v,
    const float* __restrict__ W2, const float* __restrict__ B2, int relu2, float* __restrict__ C2)
{
    __shared__ float xs[EMB * 68];
    __shared__ float w1s[EMB * EMB];
    __shared__ float w2s[HAS2 ? (EMB * EMB) : 4];

    int t = threadIdx.x;
    {
        int r = t >> 2;
        int cs = (t & 3) * 16;
        long gr = (long)blockIdx.x * 64 + r;
        float4 v[4];
        if (gr < n) {
            const float4* sp = (const float4*)(X + gr * EMB + cs);
#pragma unroll
            for (int q = 0; q < 4; ++q) v[q] = sp[q];
        } else {
            float4 z = make_float4(0.f, 0.f, 0.f, 0.f);
#pragma unroll
            for (int q = 0; q < 4; ++q) v[q] = z;
        }
#pragma unroll
        for (int q = 0; q < 4; ++q) {
            xs[(cs + q * 4 + 0) * 68 + r] = v[q].x;
            xs[(cs + q * 4 + 1) * 68 + r] = v[q].y;
            xs[(cs + q * 4 + 2) * 68 + r] = v[q].z;
            xs[(cs + q * 4 + 3) * 68 + r] = v[q].w;
        }
        const float4* wg1 = (const float4*)W1;
        float4* wl1 = (float4*)w1s;
#pragma unroll
        for (int q = 0; q < 4; ++q) wl1[t + q * 256] = wg1[t + q * 256];
        if (HAS2) {
            const float4* wg2 = (const float4*)W2;
            float4* wl2 = (float4*)w2s;
#pragma unroll
            for (int q = 0; q < 4; ++q) wl2[t + q * 256] = wg2[t + q * 256];
        }
    }
    __syncthreads();

    int r0 = (t >> 4) * 4;
    int c0 = (t & 15) * 4;
    float acc1[4][4] = {{0.f}};
    float acc2[4][4] = {{0.f}};
#pragma unroll 8
    for (int k = 0; k < EMB; ++k) {
        float4 xv = *(const float4*)&xs[k * 68 + r0];
        float4 wv = *(const float4*)&w1s[k * EMB + c0];
        float xa[4] = {xv.x, xv.y, xv.z, xv.w};
        float wa[4] = {wv.x, wv.y, wv.z, wv.w};
#pragma unroll
        for (int i = 0; i < 4; ++i)
#pragma unroll
            for (int j = 0; j < 4; ++j)
                acc1[i][j] = fmaf(xa[i], wa[j], acc1[i][j]);
        if (HAS2) {
            float4 w2v = *(const float4*)&w2s[k * EMB + c0];
            float wb[4] = {w2v.x, w2v.y, w2v.z, w2v.w};
#pragma unroll
            for (int i = 0; i < 4; ++i)
#pragma unroll
                for (int j = 0; j < 4; ++j)
                    acc2[i][j] = fmaf(xa[i], wb[j], acc2[i][j]);
        }
    }

    float4 b1v = make_float4(0.f, 0.f, 0.f, 0.f);
    if (B1) b1v = *(const float4*)&B1[c0];
#pragma unroll
    for (int i = 0; i < 4; ++i) {
        long gr = (long)blockIdx.x * 64 + r0 + i;
        if (gr < n) {
            float o0 = acc1[i][0] + b1v.x;
            float o1 = acc1[i][1] + b1v.y;
            float o2 = acc1[i][2] + b1v.z;
            float o3 = acc1[i][3] + b1v.w;
            if (relu1) { o0 = fmaxf(o0, 0.f); o1 = fmaxf(o1, 0.f); o2 = fmaxf(o2, 0.f); o3 = fmaxf(o3, 0.f); }
            if (BF1) {
                ushort4 o;
                o.x = f2bf(o0); o.y = f2bf(o1); o.z = f2bf(o2); o.w = f2bf(o3);
                *(ushort4*)((unsigned short*)C1v + gr * EMB + c0) = o;
            } else {
                *(float4*)((float*)C1v + gr * EMB + c0) = make_float4(o0, o1, o2, o3);
            }
        }
    }
    if (HAS2) {
        float4 b2v = make_float4(0.f, 0.f, 0.f, 0.f);
        if (B2) b2v = *(const float4*)&B2[c0];
#pragma unroll
        for (int i = 0; i < 4; ++i) {
            long gr = (long)blockIdx.x * 64 + r0 + i;
            if (gr < n) {
                float o0 = acc2[i][0] + b2v.x;
                float o1 = acc2[i][1] + b2v.y;
                float o2 = acc2[i][2] + b2v.z;
                float o3 = acc2[i][3] + b2v.w;
                if (relu2) { o0 = fmaxf(o0, 0.f); o1 = fmaxf(o1, 0.f); o2 = fmaxf(o2, 0.f); o3 = fmaxf(o3, 0.f); }
                *(float4*)&C2[gr * EMB + c0] = make_float4(o0, o1, o2, o3);
            }
        }
    }
}

// out[node] = relu(mean_{nbr} bf16_table[nbr] + bias + out[node])
// One node per wave. lane = 32*g + p: group g in {0,1} takes neighbors of
// parity g; lane loads 4B = 2 bf16 features at pair p. fp32 accumulate,
// shfl_xor(32) cross-group reduce, lanes g==0 do the float2 RMW.
__global__ __launch_bounds__(256) void agg_bf16_kernel(
    const unsigned short* __restrict__ tbl, const int* __restrict__ rowptr,
    const int* __restrict__ adj, const float* __restrict__ bias,
    float* __restrict__ out, int n_dst)
{
    int lane = threadIdx.x & 63;
    int node = blockIdx.x * 4 + (threadIdx.x >> 6);
    if (node >= n_dst) return;
    int p = lane & 31;
    int g = lane >> 5;
    int beg = rowptr[node];
    int end = rowptr[node + 1];
    float ax = 0.f, ay = 0.f;
    int e = beg + g;
    for (; e + 2 < end; e += 4) {
        int r0 = adj[e];
        int r1 = adj[e + 2];
        unsigned w0 = *(const unsigned*)(tbl + (long)r0 * EMB + 2 * p);
        unsigned w1 = *(const unsigned*)(tbl + (long)r1 * EMB + 2 * p);
        ax += bflo(w0) + bflo(w1);
        ay += bfhi(w0) + bfhi(w1);
    }
    if (e < end) {
        unsigned w0 = *(const unsigned*)(tbl + (long)adj[e] * EMB + 2 * p);
        ax += bflo(w0);
        ay += bfhi(w0);
    }
    ax += __shfl_xor(ax, 32);
    ay += __shfl_xor(ay, 32);
    if (g == 0) {
        int cnt = end - beg;
        float inv = 1.f / (float)(cnt > 0 ? cnt : 1);
        float2 bv = ((const float2*)bias)[p];
        float2* op = (float2*)(out + (long)node * EMB) + p;
        float2 ov = *op;
        float vx = ax * inv + bv.x + ov.x;
        float vy = ay * inv + bv.y + ov.y;
        *op = make_float2(fmaxf(vx, 0.f), fmaxf(vy, 0.f));
    }
}

extern "C" void kernel_launch(void* const* d_in, const int* in_sizes, int n_in,
                              void* d_out, int out_size, void* d_ws, size_t ws_size,
                              hipStream_t stream) {
    const float* cons_x     = (const float*)d_in[0];
    const float* var_x      = (const float*)d_in[1];
    const int*   eidx       = (const int*)d_in[3];
    const float* cons_shift = (const float*)d_in[4];
    const float* cons_scale = (const float*)d_in[5];
    const float* cons_w1    = (const float*)d_in[6];
    const float* cons_b1    = (const float*)d_in[7];
    const float* cons_w2    = (const float*)d_in[8];
    const float* cons_b2    = (const float*)d_in[9];
    const float* var_shift  = (const float*)d_in[10];
    const float* var_scale  = (const float*)d_in[11];
    const float* var_w1     = (const float*)d_in[12];
    const float* var_b1     = (const float*)d_in[13];
    const float* var_w2     = (const float*)d_in[14];
    const float* var_b2     = (const float*)d_in[15];
    const float* ll_w       = (const float*)d_in[18];
    const float* ll_b       = (const float*)d_in[19];
    const float* lr_w       = (const float*)d_in[20];

    const int nC = in_sizes[0] / 5;
    const int nV = in_sizes[1] / 19;
    const int E  = in_sizes[3] / 2;
    const int* src = eidx;       // constraint ids
    const int* dst = eidx + E;   // variable ids

    int shc = 0; while ((nC >> shc) >= 512) ++shc;
    int shv = 0; while ((nV >> shv) >= 512) ++shv;
    const int NBC = (nC + (1 << shc) - 1) >> shc;
    const int NBV = (nV + (1 << shv) - 1) >> shv;

    char* w = (char*)d_ws;
    auto alloc = [&](size_t bytes) {
        char* p = w;
        w += (bytes + 255) & ~(size_t)255;
        return p;
    };
    float* x_c = (float*)alloc((size_t)nC * EMB * 4);
    float* x_v = (float*)alloc((size_t)nV * EMB * 4);
    float* t_c = (float*)alloc((size_t)nC * EMB * 4);   // aliases: tmp_c, then embed hidden, then bf16 table
    float* t_v = (float*)alloc((size_t)nV * EMB * 4);
    uint2* tmp_c = (uint2*)t_c;
    uint2* tmp_v = (uint2*)t_v;
    unsigned short* tb_c = (unsigned short*)t_c;   // bf16 table, nC*EMB*2 <= region
    unsigned short* tb_v = (unsigned short*)t_v;
    int* rp_v  = (int*)alloc((size_t)(nV + 1) * 4);
    int* rp_c  = (int*)alloc((size_t)(nC + 1) * 4);
    int* adj_v = (int*)alloc((size_t)E * 4);
    int* adj_c = (int*)alloc((size_t)E * 4);
    int* bkt   = (int*)alloc(4096 * 4);
    int* bb_c   = bkt;
    int* bb_v   = bkt + 1024;
    int* gcur_c = bkt + 2048;
    int* gcur_v = bkt + 3072;

    auto llw = [&](int l, int d) { return ll_w + (size_t)(l * 2 + d) * EMB * EMB; };
    auto lrw = [&](int l, int d) { return lr_w + (size_t)(l * 2 + d) * EMB * EMB; };
    auto llb = [&](int l, int d) { return ll_b + (size_t)(l * 2 + d) * EMB; };

    // ---- CSR build (bucket-binned, no per-node global atomics) ----
    zero_int_kernel<<<16, 256, 0, stream>>>(bkt, 4096);
    bucket_hist_kernel<<<(E + CH - 1) / CH, 256, 0, stream>>>(src, dst, E, bb_c, bb_v, shc, shv, NBC, NBV);
    scan_buckets_kernel<<<1, 256, 0, stream>>>(bb_c, NBC, bb_v, NBV, E);
    bin_edges_kernel<<<(E + CH - 1) / CH, 256, 0, stream>>>(src, dst, E, bb_c, bb_v, gcur_c, gcur_v,
                                                            tmp_c, tmp_v, shc, shv, NBC, NBV);
    regroup2_kernel<<<NBV, 256, 0, stream>>>(tmp_v, bb_v, rp_v, adj_v, nV, shv, E, NBV);
    regroup2_kernel<<<NBC, 256, 0, stream>>>(tmp_c, bb_c, rp_c, adj_c, nC, shc, E, NBC);

    // ---- node embeddings (hidden in t_c/t_v fp32; tmp already consumed) ----
    embed1_kernel<<<(nC + 3) / 4, 256, 0, stream>>>(cons_x, cons_shift, cons_scale, cons_w1, cons_b1, t_c, nC, 5);
    gemm64_kernel<false, false><<<(nC + 63) / 64, 256, 0, stream>>>(t_c, nC, cons_w2, cons_b2, 1, x_c,
                                                                    nullptr, nullptr, 0, nullptr);
    embed1_kernel<<<(nV + 3) / 4, 256, 0, stream>>>(var_x, var_shift, var_scale, var_w1, var_b1, t_v, nV, 19);
    gemm64_kernel<false, false><<<(nV + 63) / 64, 256, 0, stream>>>(t_v, nV, var_w2, var_b2, 1, x_v,
                                                                    nullptr, nullptr, 0, nullptr);

    // ---- layer 0: t tables in bf16, u-terms fp32 in place ----
    gemm64_kernel<true, true><<<(nC + 63) / 64, 256, 0, stream>>>(x_c, nC, llw(0, 0), nullptr, 0, tb_c,
                                                                  lrw(0, 1), nullptr, 0, x_c);
    gemm64_kernel<true, true><<<(nV + 63) / 64, 256, 0, stream>>>(x_v, nV, llw(0, 1), nullptr, 0, tb_v,
                                                                  lrw(0, 0), nullptr, 0, x_v);
    agg_bf16_kernel<<<(nV + 3) / 4, 256, 0, stream>>>(tb_c, rp_v, adj_v, llb(0, 0), x_v, nV);
    agg_bf16_kernel<<<(nC + 3) / 4, 256, 0, stream>>>(tb_v, rp_c, adj_c, llb(0, 1), x_c, nC);

    // ---- layer 1 (final): only new_v reaches the output ----
    gemm64_kernel<false, true><<<(nC + 63) / 64, 256, 0, stream>>>(x_c, nC, llw(1, 0), nullptr, 0, tb_c,
                                                                   nullptr, nullptr, 0, nullptr);
    gemm64_kernel<false, false><<<(nV + 63) / 64, 256, 0, stream>>>(x_v, nV, lrw(1, 0), nullptr, 0, (float*)d_out,
                                                                    nullptr, nullptr, 0, nullptr);
    agg_bf16_kernel<<<(nV + 3) / 4, 256, 0, stream>>>(tb_c, rp_v, adj_v, llb(1, 0), (float*)d_out, nV);
}

// Round 5
// 546.843 us; speedup vs baseline: 1.7704x; 1.1603x over previous
//
#include <hip/hip_runtime.h>

#define EMB 64
#define CH 4096

// ---------------------------------------------------------------------------
// Round 5:
//  - fused_embed: prenorm + Linear(NF,64)+relu + Linear(64,64)+relu in ONE
//    kernel (64-row tile, hidden stays in LDS). Deletes the latency-bound
//    embed1 kernels (93.7us var) and 154MB of hidden round-trip traffic.
//  - tmp pairs packed to u32 (local<<23 | other): halves bin/regroup traffic.
//  - rest unchanged: bucket-binned CSR build, dual-output gemm64, bf16
//    gather tables for the agg (absmax 1.56e-2 << 6.28e-2 threshold).
// ---------------------------------------------------------------------------

static __device__ __forceinline__ unsigned short f2bf(float x) {
    union { float f; unsigned u; } v; v.f = x;
    unsigned r = v.u + 0x7fffu + ((v.u >> 16) & 1u);   // RNE
    return (unsigned short)(r >> 16);
}
static __device__ __forceinline__ float bflo(unsigned w) {
    union { unsigned u; float f; } v; v.u = w << 16; return v.f;
}
static __device__ __forceinline__ float bfhi(unsigned w) {
    union { unsigned u; float f; } v; v.u = w & 0xffff0000u; return v.f;
}

__global__ __launch_bounds__(256) void zero_int_kernel(int* __restrict__ p, int n) {
    int i = blockIdx.x * 256 + threadIdx.x;
    if (i < n) p[i] = 0;
}

__global__ __launch_bounds__(256) void bucket_hist_kernel(
    const int* __restrict__ src, const int* __restrict__ dst, int E,
    int* __restrict__ bkt_cnt_c, int* __restrict__ bkt_cnt_v,
    int shc, int shv, int NBC, int NBV)
{
    __shared__ int hc[512], hv[512];
    int t = threadIdx.x;
    int base = blockIdx.x * CH;
    int n = min(CH, E - base);
    for (int i = t; i < NBC; i += 256) hc[i] = 0;
    for (int i = t; i < NBV; i += 256) hv[i] = 0;
    __syncthreads();
    for (int li = t; li < n; li += 256) {
        atomicAdd(&hc[src[base + li] >> shc], 1);
        atomicAdd(&hv[dst[base + li] >> shv], 1);
    }
    __syncthreads();
    for (int i = t; i < NBC; i += 256) { int c = hc[i]; if (c) atomicAdd(&bkt_cnt_c[i], c); }
    for (int i = t; i < NBV; i += 256) { int c = hv[i]; if (c) atomicAdd(&bkt_cnt_v[i], c); }
}

// one block: exclusive-scan both bucket-count arrays in place; data[n] = E
__global__ __launch_bounds__(256) void scan_buckets_kernel(
    int* __restrict__ bc, int nbc, int* __restrict__ bv, int nbv, int E)
{
    __shared__ int sc[256];
    int t = threadIdx.x;
    {
        int v0 = (2 * t < nbc) ? bc[2 * t] : 0;
        int v1 = (2 * t + 1 < nbc) ? bc[2 * t + 1] : 0;
        sc[t] = v0 + v1;
        __syncthreads();
        for (int off = 1; off < 256; off <<= 1) {
            int x = (t >= off) ? sc[t - off] : 0;
            __syncthreads();
            sc[t] += x;
            __syncthreads();
        }
        int ex = (t > 0) ? sc[t - 1] : 0;
        if (2 * t < nbc) bc[2 * t] = ex;
        if (2 * t + 1 < nbc) bc[2 * t + 1] = ex + v0;
        if (t == 0) bc[nbc] = E;
        __syncthreads();
    }
    {
        int v0 = (2 * t < nbv) ? bv[2 * t] : 0;
        int v1 = (2 * t + 1 < nbv) ? bv[2 * t + 1] : 0;
        sc[t] = v0 + v1;
        __syncthreads();
        for (int off = 1; off < 256; off <<= 1) {
            int x = (t >= off) ? sc[t - off] : 0;
            __syncthreads();
            sc[t] += x;
            __syncthreads();
        }
        int ex = (t > 0) ? sc[t - 1] : 0;
        if (2 * t < nbv) bv[2 * t] = ex;
        if (2 * t + 1 < nbv) bv[2 * t + 1] = ex + v0;
        if (t == 0) bv[nbv] = E;
    }
}

// Phase 1: per-chunk LDS binning; packed u32 {local_node<<23 | other}.
__global__ __launch_bounds__(256) void bin_edges_kernel(
    const int* __restrict__ src, const int* __restrict__ dst, int E,
    const int* __restrict__ bb_c, const int* __restrict__ bb_v,
    int* __restrict__ gcur_c, int* __restrict__ gcur_v,
    unsigned* __restrict__ tmp_c, unsigned* __restrict__ tmp_v,
    int shc, int shv, int NBC, int NBV)
{
    __shared__ int hc[512], hv[512];
    int t = threadIdx.x;
    int base = blockIdx.x * CH;
    int n = min(CH, E - base);
    unsigned mc = (1u << shc) - 1u, mv = (1u << shv) - 1u;

    for (int i = t; i < NBC; i += 256) hc[i] = 0;
    for (int i = t; i < NBV; i += 256) hv[i] = 0;
    __syncthreads();

    int ss[16], dd[16];
#pragma unroll
    for (int q = 0; q < 16; ++q) {
        int li = t + q * 256;
        bool ok = li < n;
        ss[q] = ok ? src[base + li] : -1;
        dd[q] = ok ? dst[base + li] : -1;
        if (ok) {
            atomicAdd(&hc[ss[q] >> shc], 1);
            atomicAdd(&hv[dd[q] >> shv], 1);
        }
    }
    __syncthreads();

    for (int i = t; i < NBC; i += 256) {
        int c = hc[i];
        hc[i] = c ? (bb_c[i] + atomicAdd(&gcur_c[i], c)) : 0;
    }
    for (int i = t; i < NBV; i += 256) {
        int c = hv[i];
        hv[i] = c ? (bb_v[i] + atomicAdd(&gcur_v[i], c)) : 0;
    }
    __syncthreads();

#pragma unroll
    for (int q = 0; q < 16; ++q) {
        int li = t + q * 256;
        if (li < n) {
            unsigned s = (unsigned)ss[q], d = (unsigned)dd[q];
            int pc = atomicAdd(&hc[s >> shc], 1);
            tmp_c[pc] = ((s & mc) << 23) | d;
            int pv = atomicAdd(&hv[d >> shv], 1);
            tmp_v[pv] = ((d & mv) << 23) | s;
        }
    }
}

// Phase 2: wg-per-bucket. LDS per-node hist -> scan -> rp; rank -> adj.
__global__ __launch_bounds__(256) void regroup2_kernel(
    const unsigned* __restrict__ tmp, const int* __restrict__ bb,
    int* __restrict__ rp, int* __restrict__ adj, int n_nodes, int sh, int E, int nb)
{
    __shared__ int cnt[512];
    __shared__ int offs[512];
    __shared__ int sc[256];
    int t = threadIdx.x;
    int b = blockIdx.x;
    int node0 = b << sh;
    int node1 = min(node0 + (1 << sh), n_nodes);
    int nn = node1 - node0;
    for (int i = t; i < nn; i += 256) cnt[i] = 0;
    __syncthreads();
    int beg = bb[b], end = bb[b + 1];
    for (int e = beg + t; e < end; e += 256)
        atomicAdd(&cnt[tmp[e] >> 23], 1);
    __syncthreads();
    int v0 = (2 * t < nn) ? cnt[2 * t] : 0;
    int v1 = (2 * t + 1 < nn) ? cnt[2 * t + 1] : 0;
    sc[t] = v0 + v1;
    __syncthreads();
    for (int off = 1; off < 256; off <<= 1) {
        int x = (t >= off) ? sc[t - off] : 0;
        __syncthreads();
        sc[t] += x;
        __syncthreads();
    }
    int ex = (t > 0) ? sc[t - 1] : 0;
    if (2 * t < nn) offs[2 * t] = ex;
    if (2 * t + 1 < nn) offs[2 * t + 1] = ex + v0;
    __syncthreads();
    for (int i = t; i < nn; i += 256) {
        rp[node0 + i] = beg + offs[i];
        cnt[i] = 0;
    }
    if (b == nb - 1 && t == 0) rp[n_nodes] = E;
    __syncthreads();
    for (int e = beg + t; e < end; e += 256) {
        unsigned p = tmp[e];
        int d = (int)(p >> 23);
        int r = atomicAdd(&cnt[d], 1);
        adj[beg + offs[d] + r] = (int)(p & 0x7fffffu);
    }
}

// Fused MLP embed: out = relu(relu(((x+shift)*scale)@W1 + b1)@W2 + b2)
// 64-row tile per block; hidden lives in LDS; no HBM round-trip.
template <int NF>
__global__ __launch_bounds__(256) void fused_embed_kernel(
    const float* __restrict__ x, const float* __restrict__ shift, const float* __restrict__ scale,
    const float* __restrict__ w1, const float* __restrict__ b1,
    const float* __restrict__ w2, const float* __restrict__ b2,
    float* __restrict__ out, int n)
{
    __shared__ float xs[NF * 68];     // xs[k*68+r] pre-normalized, transposed
    __shared__ float w1s[NF * EMB];
    __shared__ float w2s[EMB * EMB];
    __shared__ float hs[EMB * 68];    // hidden transposed [k2][r]
    __shared__ float b1s[EMB], b2s[EMB];

    int t = threadIdx.x;
    long row0 = (long)blockIdx.x * 64;
    int nrow = (int)((n - row0 < 64) ? (n - row0) : 64);

    for (int i = t; i < NF * EMB; i += 256) w1s[i] = w1[i];
    if (t < EMB) { b1s[t] = b1[t]; b2s[t] = b2[t]; }
    {
        const float4* wg2 = (const float4*)w2;
        float4* wl2 = (float4*)w2s;
#pragma unroll
        for (int q = 0; q < 4; ++q) wl2[t + q * 256] = wg2[t + q * 256];
    }
    for (int i = t; i < 64 * NF; i += 256) {
        int r = i / NF, k = i - r * NF;
        float v = (r < nrow) ? x[row0 * NF + i] : 0.f;
        xs[k * 68 + r] = (v + shift[k]) * scale[k];
    }
    __syncthreads();

    int r0 = (t >> 4) * 4;
    int c0 = (t & 15) * 4;
    {
        float a1[4][4] = {{0.f}};
#pragma unroll
        for (int k = 0; k < NF; ++k) {
            float4 xv = *(const float4*)&xs[k * 68 + r0];
            float4 wv = *(const float4*)&w1s[k * EMB + c0];
            float xa[4] = {xv.x, xv.y, xv.z, xv.w};
            float wa[4] = {wv.x, wv.y, wv.z, wv.w};
#pragma unroll
            for (int i = 0; i < 4; ++i)
#pragma unroll
                for (int j = 0; j < 4; ++j)
                    a1[i][j] = fmaf(xa[i], wa[j], a1[i][j]);
        }
        // hidden^T: hs[k2][r], float4 over the row block
#pragma unroll
        for (int j = 0; j < 4; ++j) {
            float b = b1s[c0 + j];
            float4 o;
            o.x = fmaxf(a1[0][j] + b, 0.f);
            o.y = fmaxf(a1[1][j] + b, 0.f);
            o.z = fmaxf(a1[2][j] + b, 0.f);
            o.w = fmaxf(a1[3][j] + b, 0.f);
            *(float4*)&hs[(c0 + j) * 68 + r0] = o;
        }
    }
    __syncthreads();

    float a2[4][4] = {{0.f}};
#pragma unroll 8
    for (int k = 0; k < EMB; ++k) {
        float4 xv = *(const float4*)&hs[k * 68 + r0];
        float4 wv = *(const float4*)&w2s[k * EMB + c0];
        float xa[4] = {xv.x, xv.y, xv.z, xv.w};
        float wa[4] = {wv.x, wv.y, wv.z, wv.w};
#pragma unroll
        for (int i = 0; i < 4; ++i)
#pragma unroll
            for (int j = 0; j < 4; ++j)
                a2[i][j] = fmaf(xa[i], wa[j], a2[i][j]);
    }
    float4 b2v = *(const float4*)&b2s[c0];
#pragma unroll
    for (int i = 0; i < 4; ++i) {
        long gr = row0 + r0 + i;
        if (gr < n) {
            float4 o;
            o.x = fmaxf(a2[i][0] + b2v.x, 0.f);
            o.y = fmaxf(a2[i][1] + b2v.y, 0.f);
            o.z = fmaxf(a2[i][2] + b2v.z, 0.f);
            o.w = fmaxf(a2[i][3] + b2v.w, 0.f);
            *(float4*)&out[gr * EMB + c0] = o;
        }
    }
}

// C1 = act(X@W1 [+B1]) (fp32 or bf16 out); optionally C2 = act(X@W2 [+B2])
// fp32, sharing the X tile. C2 may alias X.
template <bool HAS2, bool BF1>
__global__ __launch_bounds__(256) void gemm64_kernel(
    const float* __restrict__ X, int n,
    const float* __restrict__ W1, const float* __restrict__ B1, int relu1, void* __restrict__ C1v,
    const float* __restrict__ W2, const float* __restrict__ B2, int relu2, float* __restrict__ C2)
{
    __shared__ float xs[EMB * 68];
    __shared__ float w1s[EMB * EMB];
    __shared__ float w2s[HAS2 ? (EMB * EMB) : 4];

    int t = threadIdx.x;
    {
        int r = t >> 2;
        int cs = (t & 3) * 16;
        long gr = (long)blockIdx.x * 64 + r;
        float4 v[4];
        if (gr < n) {
            const float4* sp = (const float4*)(X + gr * EMB + cs);
#pragma unroll
            for (int q = 0; q < 4; ++q) v[q] = sp[q];
        } else {
            float4 z = make_float4(0.f, 0.f, 0.f, 0.f);
#pragma unroll
            for (int q = 0; q < 4; ++q) v[q] = z;
        }
#pragma unroll
        for (int q = 0; q < 4; ++q) {
            xs[(cs + q * 4 + 0) * 68 + r] = v[q].x;
            xs[(cs + q * 4 + 1) * 68 + r] = v[q].y;
            xs[(cs + q * 4 + 2) * 68 + r] = v[q].z;
            xs[(cs + q * 4 + 3) * 68 + r] = v[q].w;
        }
        const float4* wg1 = (const float4*)W1;
        float4* wl1 = (float4*)w1s;
#pragma unroll
        for (int q = 0; q < 4; ++q) wl1[t + q * 256] = wg1[t + q * 256];
        if (HAS2) {
            const float4* wg2 = (const float4*)W2;
            float4* wl2 = (float4*)w2s;
#pragma unroll
            for (int q = 0; q < 4; ++q) wl2[t + q * 256] = wg2[t + q * 256];
        }
    }
    __syncthreads();

    int r0 = (t >> 4) * 4;
    int c0 = (t & 15) * 4;
    float acc1[4][4] = {{0.f}};
    float acc2[4][4] = {{0.f}};
#pragma unroll 8
    for (int k = 0; k < EMB; ++k) {
        float4 xv = *(const float4*)&xs[k * 68 + r0];
        float4 wv = *(const float4*)&w1s[k * EMB + c0];
        float xa[4] = {xv.x, xv.y, xv.z, xv.w};
        float wa[4] = {wv.x, wv.y, wv.z, wv.w};
#pragma unroll
        for (int i = 0; i < 4; ++i)
#pragma unroll
            for (int j = 0; j < 4; ++j)
                acc1[i][j] = fmaf(xa[i], wa[j], acc1[i][j]);
        if (HAS2) {
            float4 w2v = *(const float4*)&w2s[k * EMB + c0];
            float wb[4] = {w2v.x, w2v.y, w2v.z, w2v.w};
#pragma unroll
            for (int i = 0; i < 4; ++i)
#pragma unroll
                for (int j = 0; j < 4; ++j)
                    acc2[i][j] = fmaf(xa[i], wb[j], acc2[i][j]);
        }
    }

    float4 b1v = make_float4(0.f, 0.f, 0.f, 0.f);
    if (B1) b1v = *(const float4*)&B1[c0];
#pragma unroll
    for (int i = 0; i < 4; ++i) {
        long gr = (long)blockIdx.x * 64 + r0 + i;
        if (gr < n) {
            float o0 = acc1[i][0] + b1v.x;
            float o1 = acc1[i][1] + b1v.y;
            float o2 = acc1[i][2] + b1v.z;
            float o3 = acc1[i][3] + b1v.w;
            if (relu1) { o0 = fmaxf(o0, 0.f); o1 = fmaxf(o1, 0.f); o2 = fmaxf(o2, 0.f); o3 = fmaxf(o3, 0.f); }
            if (BF1) {
                ushort4 o;
                o.x = f2bf(o0); o.y = f2bf(o1); o.z = f2bf(o2); o.w = f2bf(o3);
                *(ushort4*)((unsigned short*)C1v + gr * EMB + c0) = o;
            } else {
                *(float4*)((float*)C1v + gr * EMB + c0) = make_float4(o0, o1, o2, o3);
            }
        }
    }
    if (HAS2) {
        float4 b2v = make_float4(0.f, 0.f, 0.f, 0.f);
        if (B2) b2v = *(const float4*)&B2[c0];
#pragma unroll
        for (int i = 0; i < 4; ++i) {
            long gr = (long)blockIdx.x * 64 + r0 + i;
            if (gr < n) {
                float o0 = acc2[i][0] + b2v.x;
                float o1 = acc2[i][1] + b2v.y;
                float o2 = acc2[i][2] + b2v.z;
                float o3 = acc2[i][3] + b2v.w;
                if (relu2) { o0 = fmaxf(o0, 0.f); o1 = fmaxf(o1, 0.f); o2 = fmaxf(o2, 0.f); o3 = fmaxf(o3, 0.f); }
                *(float4*)&C2[gr * EMB + c0] = make_float4(o0, o1, o2, o3);
            }
        }
    }
}

// out[node] = relu(mean_{nbr} bf16_table[nbr] + bias + out[node])
__global__ __launch_bounds__(256) void agg_bf16_kernel(
    const unsigned short* __restrict__ tbl, const int* __restrict__ rowptr,
    const int* __restrict__ adj, const float* __restrict__ bias,
    float* __restrict__ out, int n_dst)
{
    int lane = threadIdx.x & 63;
    int node = blockIdx.x * 4 + (threadIdx.x >> 6);
    if (node >= n_dst) return;
    int p = lane & 31;
    int g = lane >> 5;
    int beg = rowptr[node];
    int end = rowptr[node + 1];
    float ax = 0.f, ay = 0.f;
    int e = beg + g;
    for (; e + 2 < end; e += 4) {
        int r0 = adj[e];
        int r1 = adj[e + 2];
        unsigned w0 = *(const unsigned*)(tbl + (long)r0 * EMB + 2 * p);
        unsigned w1 = *(const unsigned*)(tbl + (long)r1 * EMB + 2 * p);
        ax += bflo(w0) + bflo(w1);
        ay += bfhi(w0) + bfhi(w1);
    }
    if (e < end) {
        unsigned w0 = *(const unsigned*)(tbl + (long)adj[e] * EMB + 2 * p);
        ax += bflo(w0);
        ay += bfhi(w0);
    }
    ax += __shfl_xor(ax, 32);
    ay += __shfl_xor(ay, 32);
    if (g == 0) {
        int cnt = end - beg;
        float inv = 1.f / (float)(cnt > 0 ? cnt : 1);
        float2 bv = ((const float2*)bias)[p];
        float2* op = (float2*)(out + (long)node * EMB) + p;
        float2 ov = *op;
        float vx = ax * inv + bv.x + ov.x;
        float vy = ay * inv + bv.y + ov.y;
        *op = make_float2(fmaxf(vx, 0.f), fmaxf(vy, 0.f));
    }
}

extern "C" void kernel_launch(void* const* d_in, const int* in_sizes, int n_in,
                              void* d_out, int out_size, void* d_ws, size_t ws_size,
                              hipStream_t stream) {
    const float* cons_x     = (const float*)d_in[0];
    const float* var_x      = (const float*)d_in[1];
    const int*   eidx       = (const int*)d_in[3];
    const float* cons_shift = (const float*)d_in[4];
    const float* cons_scale = (const float*)d_in[5];
    const float* cons_w1    = (const float*)d_in[6];
    const float* cons_b1    = (const float*)d_in[7];
    const float* cons_w2    = (const float*)d_in[8];
    const float* cons_b2    = (const float*)d_in[9];
    const float* var_shift  = (const float*)d_in[10];
    const float* var_scale  = (const float*)d_in[11];
    const float* var_w1     = (const float*)d_in[12];
    const float* var_b1     = (const float*)d_in[13];
    const float* var_w2     = (const float*)d_in[14];
    const float* var_b2     = (const float*)d_in[15];
    const float* ll_w       = (const float*)d_in[18];
    const float* ll_b       = (const float*)d_in[19];
    const float* lr_w       = (const float*)d_in[20];

    const int nC = in_sizes[0] / 5;
    const int nV = in_sizes[1] / 19;
    const int E  = in_sizes[3] / 2;
    const int* src = eidx;       // constraint ids
    const int* dst = eidx + E;   // variable ids

    int shc = 0; while ((nC >> shc) >= 512) ++shc;
    int shv = 0; while ((nV >> shv) >= 512) ++shv;
    const int NBC = (nC + (1 << shc) - 1) >> shc;
    const int NBV = (nV + (1 << shv) - 1) >> shv;

    char* w = (char*)d_ws;
    auto alloc = [&](size_t bytes) {
        char* p = w;
        w += (bytes + 255) & ~(size_t)255;
        return p;
    };
    float* x_c = (float*)alloc((size_t)nC * EMB * 4);
    float* x_v = (float*)alloc((size_t)nV * EMB * 4);
    float* t_c = (float*)alloc((size_t)nC * EMB * 4);   // aliases: tmp_c, then bf16 table
    float* t_v = (float*)alloc((size_t)nV * EMB * 4);
    unsigned* tmp_c = (unsigned*)t_c;                   // E*4 = 8MB <= region
    unsigned* tmp_v = (unsigned*)t_v;
    unsigned short* tb_c = (unsigned short*)t_c;
    unsigned short* tb_v = (unsigned short*)t_v;
    int* rp_v  = (int*)alloc((size_t)(nV + 1) * 4);
    int* rp_c  = (int*)alloc((size_t)(nC + 1) * 4);
    int* adj_v = (int*)alloc((size_t)E * 4);
    int* adj_c = (int*)alloc((size_t)E * 4);
    int* bkt   = (int*)alloc(4096 * 4);
    int* bb_c   = bkt;
    int* bb_v   = bkt + 1024;
    int* gcur_c = bkt + 2048;
    int* gcur_v = bkt + 3072;

    auto llw = [&](int l, int d) { return ll_w + (size_t)(l * 2 + d) * EMB * EMB; };
    auto lrw = [&](int l, int d) { return lr_w + (size_t)(l * 2 + d) * EMB * EMB; };
    auto llb = [&](int l, int d) { return ll_b + (size_t)(l * 2 + d) * EMB; };

    // ---- CSR build ----
    zero_int_kernel<<<16, 256, 0, stream>>>(bkt, 4096);
    bucket_hist_kernel<<<(E + CH - 1) / CH, 256, 0, stream>>>(src, dst, E, bb_c, bb_v, shc, shv, NBC, NBV);
    scan_buckets_kernel<<<1, 256, 0, stream>>>(bb_c, NBC, bb_v, NBV, E);
    bin_edges_kernel<<<(E + CH - 1) / CH, 256, 0, stream>>>(src, dst, E, bb_c, bb_v, gcur_c, gcur_v,
                                                            tmp_c, tmp_v, shc, shv, NBC, NBV);
    regroup2_kernel<<<NBV, 256, 0, stream>>>(tmp_v, bb_v, rp_v, adj_v, nV, shv, E, NBV);
    regroup2_kernel<<<NBC, 256, 0, stream>>>(tmp_c, bb_c, rp_c, adj_c, nC, shc, E, NBC);

    // ---- node embeddings (fused MLP; tmp consumed, t_* free) ----
    fused_embed_kernel<5><<<(nC + 63) / 64, 256, 0, stream>>>(
        cons_x, cons_shift, cons_scale, cons_w1, cons_b1, cons_w2, cons_b2, x_c, nC);
    fused_embed_kernel<19><<<(nV + 63) / 64, 256, 0, stream>>>(
        var_x, var_shift, var_scale, var_w1, var_b1, var_w2, var_b2, x_v, nV);

    // ---- layer 0: t tables in bf16, u-terms fp32 in place ----
    gemm64_kernel<true, true><<<(nC + 63) / 64, 256, 0, stream>>>(x_c, nC, llw(0, 0), nullptr, 0, tb_c,
                                                                  lrw(0, 1), nullptr, 0, x_c);
    gemm64_kernel<true, true><<<(nV + 63) / 64, 256, 0, stream>>>(x_v, nV, llw(0, 1), nullptr, 0, tb_v,
                                                                  lrw(0, 0), nullptr, 0, x_v);
    agg_bf16_kernel<<<(nV + 3) / 4, 256, 0, stream>>>(tb_c, rp_v, adj_v, llb(0, 0), x_v, nV);
    agg_bf16_kernel<<<(nC + 3) / 4, 256, 0, stream>>>(tb_v, rp_c, adj_c, llb(0, 1), x_c, nC);

    // ---- layer 1 (final): only new_v reaches the output ----
    gemm64_kernel<false, true><<<(nC + 63) / 64, 256, 0, stream>>>(x_c, nC, llw(1, 0), nullptr, 0, tb_c,
                                                                   nullptr, nullptr, 0, nullptr);
    gemm64_kernel<false, false><<<(nV + 63) / 64, 256, 0, stream>>>(x_v, nV, lrw(1, 0), nullptr, 0, (float*)d_out,
                                                                    nullptr, nullptr, 0, nullptr);
    agg_bf16_kernel<<<(nV + 3) / 4, 256, 0, stream>>>(tb_c, rp_v, adj_v, llb(1, 0), (float*)d_out, nV);
}

// Round 6
// 499.510 us; speedup vs baseline: 1.9381x; 1.0948x over previous
//
#include <hip/hip_runtime.h>

#define EMB 64
#define CH 4096

// ---------------------------------------------------------------------------
// Round 6: agg restructure. r5 counters showed agg is NOT bandwidth-saturated
// (3.9TB/s streamed, 1.4TB/s fabric, VALUBusy 38%) -> issue/latency-bound.
// New gather layout: lane = 16*g + p; lane loads uint2 (8B = 4 bf16) of row
// adj[slot g], so one wave64 load covers 4 rows (512B) vs 2 rows before;
// unroll 2 -> 8 rows in flight/iter. shfl_xor(16)+(32) reduce; float4 RMW.
// Identical arithmetic (fp32 accum) -> absmax unchanged.
// ---------------------------------------------------------------------------

static __device__ __forceinline__ unsigned short f2bf(float x) {
    union { float f; unsigned u; } v; v.f = x;
    unsigned r = v.u + 0x7fffu + ((v.u >> 16) & 1u);   // RNE
    return (unsigned short)(r >> 16);
}
static __device__ __forceinline__ float bflo(unsigned w) {
    union { unsigned u; float f; } v; v.u = w << 16; return v.f;
}
static __device__ __forceinline__ float bfhi(unsigned w) {
    union { unsigned u; float f; } v; v.u = w & 0xffff0000u; return v.f;
}

__global__ __launch_bounds__(256) void zero_int_kernel(int* __restrict__ p, int n) {
    int i = blockIdx.x * 256 + threadIdx.x;
    if (i < n) p[i] = 0;
}

__global__ __launch_bounds__(256) void bucket_hist_kernel(
    const int* __restrict__ src, const int* __restrict__ dst, int E,
    int* __restrict__ bkt_cnt_c, int* __restrict__ bkt_cnt_v,
    int shc, int shv, int NBC, int NBV)
{
    __shared__ int hc[512], hv[512];
    int t = threadIdx.x;
    int base = blockIdx.x * CH;
    int n = min(CH, E - base);
    for (int i = t; i < NBC; i += 256) hc[i] = 0;
    for (int i = t; i < NBV; i += 256) hv[i] = 0;
    __syncthreads();
    for (int li = t; li < n; li += 256) {
        atomicAdd(&hc[src[base + li] >> shc], 1);
        atomicAdd(&hv[dst[base + li] >> shv], 1);
    }
    __syncthreads();
    for (int i = t; i < NBC; i += 256) { int c = hc[i]; if (c) atomicAdd(&bkt_cnt_c[i], c); }
    for (int i = t; i < NBV; i += 256) { int c = hv[i]; if (c) atomicAdd(&bkt_cnt_v[i], c); }
}

// one block: exclusive-scan both bucket-count arrays in place; data[n] = E
__global__ __launch_bounds__(256) void scan_buckets_kernel(
    int* __restrict__ bc, int nbc, int* __restrict__ bv, int nbv, int E)
{
    __shared__ int sc[256];
    int t = threadIdx.x;
    {
        int v0 = (2 * t < nbc) ? bc[2 * t] : 0;
        int v1 = (2 * t + 1 < nbc) ? bc[2 * t + 1] : 0;
        sc[t] = v0 + v1;
        __syncthreads();
        for (int off = 1; off < 256; off <<= 1) {
            int x = (t >= off) ? sc[t - off] : 0;
            __syncthreads();
            sc[t] += x;
            __syncthreads();
        }
        int ex = (t > 0) ? sc[t - 1] : 0;
        if (2 * t < nbc) bc[2 * t] = ex;
        if (2 * t + 1 < nbc) bc[2 * t + 1] = ex + v0;
        if (t == 0) bc[nbc] = E;
        __syncthreads();
    }
    {
        int v0 = (2 * t < nbv) ? bv[2 * t] : 0;
        int v1 = (2 * t + 1 < nbv) ? bv[2 * t + 1] : 0;
        sc[t] = v0 + v1;
        __syncthreads();
        for (int off = 1; off < 256; off <<= 1) {
            int x = (t >= off) ? sc[t - off] : 0;
            __syncthreads();
            sc[t] += x;
            __syncthreads();
        }
        int ex = (t > 0) ? sc[t - 1] : 0;
        if (2 * t < nbv) bv[2 * t] = ex;
        if (2 * t + 1 < nbv) bv[2 * t + 1] = ex + v0;
        if (t == 0) bv[nbv] = E;
    }
}

// Phase 1: per-chunk LDS binning; packed u32 {local_node<<23 | other}.
__global__ __launch_bounds__(256) void bin_edges_kernel(
    const int* __restrict__ src, const int* __restrict__ dst, int E,
    const int* __restrict__ bb_c, const int* __restrict__ bb_v,
    int* __restrict__ gcur_c, int* __restrict__ gcur_v,
    unsigned* __restrict__ tmp_c, unsigned* __restrict__ tmp_v,
    int shc, int shv, int NBC, int NBV)
{
    __shared__ int hc[512], hv[512];
    int t = threadIdx.x;
    int base = blockIdx.x * CH;
    int n = min(CH, E - base);
    unsigned mc = (1u << shc) - 1u, mv = (1u << shv) - 1u;

    for (int i = t; i < NBC; i += 256) hc[i] = 0;
    for (int i = t; i < NBV; i += 256) hv[i] = 0;
    __syncthreads();

    int ss[16], dd[16];
#pragma unroll
    for (int q = 0; q < 16; ++q) {
        int li = t + q * 256;
        bool ok = li < n;
        ss[q] = ok ? src[base + li] : -1;
        dd[q] = ok ? dst[base + li] : -1;
        if (ok) {
            atomicAdd(&hc[ss[q] >> shc], 1);
            atomicAdd(&hv[dd[q] >> shv], 1);
        }
    }
    __syncthreads();

    for (int i = t; i < NBC; i += 256) {
        int c = hc[i];
        hc[i] = c ? (bb_c[i] + atomicAdd(&gcur_c[i], c)) : 0;
    }
    for (int i = t; i < NBV; i += 256) {
        int c = hv[i];
        hv[i] = c ? (bb_v[i] + atomicAdd(&gcur_v[i], c)) : 0;
    }
    __syncthreads();

#pragma unroll
    for (int q = 0; q < 16; ++q) {
        int li = t + q * 256;
        if (li < n) {
            unsigned s = (unsigned)ss[q], d = (unsigned)dd[q];
            int pc = atomicAdd(&hc[s >> shc], 1);
            tmp_c[pc] = ((s & mc) << 23) | d;
            int pv = atomicAdd(&hv[d >> shv], 1);
            tmp_v[pv] = ((d & mv) << 23) | s;
        }
    }
}

// Phase 2: wg-per-bucket. LDS per-node hist -> scan -> rp; rank -> adj.
__global__ __launch_bounds__(256) void regroup2_kernel(
    const unsigned* __restrict__ tmp, const int* __restrict__ bb,
    int* __restrict__ rp, int* __restrict__ adj, int n_nodes, int sh, int E, int nb)
{
    __shared__ int cnt[512];
    __shared__ int offs[512];
    __shared__ int sc[256];
    int t = threadIdx.x;
    int b = blockIdx.x;
    int node0 = b << sh;
    int node1 = min(node0 + (1 << sh), n_nodes);
    int nn = node1 - node0;
    for (int i = t; i < nn; i += 256) cnt[i] = 0;
    __syncthreads();
    int beg = bb[b], end = bb[b + 1];
    for (int e = beg + t; e < end; e += 256)
        atomicAdd(&cnt[tmp[e] >> 23], 1);
    __syncthreads();
    int v0 = (2 * t < nn) ? cnt[2 * t] : 0;
    int v1 = (2 * t + 1 < nn) ? cnt[2 * t + 1] : 0;
    sc[t] = v0 + v1;
    __syncthreads();
    for (int off = 1; off < 256; off <<= 1) {
        int x = (t >= off) ? sc[t - off] : 0;
        __syncthreads();
        sc[t] += x;
        __syncthreads();
    }
    int ex = (t > 0) ? sc[t - 1] : 0;
    if (2 * t < nn) offs[2 * t] = ex;
    if (2 * t + 1 < nn) offs[2 * t + 1] = ex + v0;
    __syncthreads();
    for (int i = t; i < nn; i += 256) {
        rp[node0 + i] = beg + offs[i];
        cnt[i] = 0;
    }
    if (b == nb - 1 && t == 0) rp[n_nodes] = E;
    __syncthreads();
    for (int e = beg + t; e < end; e += 256) {
        unsigned p = tmp[e];
        int d = (int)(p >> 23);
        int r = atomicAdd(&cnt[d], 1);
        adj[beg + offs[d] + r] = (int)(p & 0x7fffffu);
    }
}

// Fused MLP embed: out = relu(relu(((x+shift)*scale)@W1 + b1)@W2 + b2)
template <int NF>
__global__ __launch_bounds__(256) void fused_embed_kernel(
    const float* __restrict__ x, const float* __restrict__ shift, const float* __restrict__ scale,
    const float* __restrict__ w1, const float* __restrict__ b1,
    const float* __restrict__ w2, const float* __restrict__ b2,
    float* __restrict__ out, int n)
{
    __shared__ float xs[NF * 68];
    __shared__ float w1s[NF * EMB];
    __shared__ float w2s[EMB * EMB];
    __shared__ float hs[EMB * 68];
    __shared__ float b1s[EMB], b2s[EMB];

    int t = threadIdx.x;
    long row0 = (long)blockIdx.x * 64;
    int nrow = (int)((n - row0 < 64) ? (n - row0) : 64);

    for (int i = t; i < NF * EMB; i += 256) w1s[i] = w1[i];
    if (t < EMB) { b1s[t] = b1[t]; b2s[t] = b2[t]; }
    {
        const float4* wg2 = (const float4*)w2;
        float4* wl2 = (float4*)w2s;
#pragma unroll
        for (int q = 0; q < 4; ++q) wl2[t + q * 256] = wg2[t + q * 256];
    }
    for (int i = t; i < 64 * NF; i += 256) {
        int r = i / NF, k = i - r * NF;
        float v = (r < nrow) ? x[row0 * NF + i] : 0.f;
        xs[k * 68 + r] = (v + shift[k]) * scale[k];
    }
    __syncthreads();

    int r0 = (t >> 4) * 4;
    int c0 = (t & 15) * 4;
    {
        float a1[4][4] = {{0.f}};
#pragma unroll
        for (int k = 0; k < NF; ++k) {
            float4 xv = *(const float4*)&xs[k * 68 + r0];
            float4 wv = *(const float4*)&w1s[k * EMB + c0];
            float xa[4] = {xv.x, xv.y, xv.z, xv.w};
            float wa[4] = {wv.x, wv.y, wv.z, wv.w};
#pragma unroll
            for (int i = 0; i < 4; ++i)
#pragma unroll
                for (int j = 0; j < 4; ++j)
                    a1[i][j] = fmaf(xa[i], wa[j], a1[i][j]);
        }
#pragma unroll
        for (int j = 0; j < 4; ++j) {
            float b = b1s[c0 + j];
            float4 o;
            o.x = fmaxf(a1[0][j] + b, 0.f);
            o.y = fmaxf(a1[1][j] + b, 0.f);
            o.z = fmaxf(a1[2][j] + b, 0.f);
            o.w = fmaxf(a1[3][j] + b, 0.f);
            *(float4*)&hs[(c0 + j) * 68 + r0] = o;
        }
    }
    __syncthreads();

    float a2[4][4] = {{0.f}};
#pragma unroll 8
    for (int k = 0; k < EMB; ++k) {
        float4 xv = *(const float4*)&hs[k * 68 + r0];
        float4 wv = *(const float4*)&w2s[k * EMB + c0];
        float xa[4] = {xv.x, xv.y, xv.z, xv.w};
        float wa[4] = {wv.x, wv.y, wv.z, wv.w};
#pragma unroll
        for (int i = 0; i < 4; ++i)
#pragma unroll
            for (int j = 0; j < 4; ++j)
                a2[i][j] = fmaf(xa[i], wa[j], a2[i][j]);
    }
    float4 b2v = *(const float4*)&b2s[c0];
#pragma unroll
    for (int i = 0; i < 4; ++i) {
        long gr = row0 + r0 + i;
        if (gr < n) {
            float4 o;
            o.x = fmaxf(a2[i][0] + b2v.x, 0.f);
            o.y = fmaxf(a2[i][1] + b2v.y, 0.f);
            o.z = fmaxf(a2[i][2] + b2v.z, 0.f);
            o.w = fmaxf(a2[i][3] + b2v.w, 0.f);
            *(float4*)&out[gr * EMB + c0] = o;
        }
    }
}

// C1 = act(X@W1 [+B1]) (fp32 or bf16 out); optionally C2 = act(X@W2 [+B2])
// fp32, sharing the X tile. C2 may alias X.
template <bool HAS2, bool BF1>
__global__ __launch_bounds__(256) void gemm64_kernel(
    const float* __restrict__ X, int n,
    const float* __restrict__ W1, const float* __restrict__ B1, int relu1, void* __restrict__ C1v,
    const float* __restrict__ W2, const float* __restrict__ B2, int relu2, float* __restrict__ C2)
{
    __shared__ float xs[EMB * 68];
    __shared__ float w1s[EMB * EMB];
    __shared__ float w2s[HAS2 ? (EMB * EMB) : 4];

    int t = threadIdx.x;
    {
        int r = t >> 2;
        int cs = (t & 3) * 16;
        long gr = (long)blockIdx.x * 64 + r;
        float4 v[4];
        if (gr < n) {
            const float4* sp = (const float4*)(X + gr * EMB + cs);
#pragma unroll
            for (int q = 0; q < 4; ++q) v[q] = sp[q];
        } else {
            float4 z = make_float4(0.f, 0.f, 0.f, 0.f);
#pragma unroll
            for (int q = 0; q < 4; ++q) v[q] = z;
        }
#pragma unroll
        for (int q = 0; q < 4; ++q) {
            xs[(cs + q * 4 + 0) * 68 + r] = v[q].x;
            xs[(cs + q * 4 + 1) * 68 + r] = v[q].y;
            xs[(cs + q * 4 + 2) * 68 + r] = v[q].z;
            xs[(cs + q * 4 + 3) * 68 + r] = v[q].w;
        }
        const float4* wg1 = (const float4*)W1;
        float4* wl1 = (float4*)w1s;
#pragma unroll
        for (int q = 0; q < 4; ++q) wl1[t + q * 256] = wg1[t + q * 256];
        if (HAS2) {
            const float4* wg2 = (const float4*)W2;
            float4* wl2 = (float4*)w2s;
#pragma unroll
            for (int q = 0; q < 4; ++q) wl2[t + q * 256] = wg2[t + q * 256];
        }
    }
    __syncthreads();

    int r0 = (t >> 4) * 4;
    int c0 = (t & 15) * 4;
    float acc1[4][4] = {{0.f}};
    float acc2[4][4] = {{0.f}};
#pragma unroll 8
    for (int k = 0; k < EMB; ++k) {
        float4 xv = *(const float4*)&xs[k * 68 + r0];
        float4 wv = *(const float4*)&w1s[k * EMB + c0];
        float xa[4] = {xv.x, xv.y, xv.z, xv.w};
        float wa[4] = {wv.x, wv.y, wv.z, wv.w};
#pragma unroll
        for (int i = 0; i < 4; ++i)
#pragma unroll
            for (int j = 0; j < 4; ++j)
                acc1[i][j] = fmaf(xa[i], wa[j], acc1[i][j]);
        if (HAS2) {
            float4 w2v = *(const float4*)&w2s[k * EMB + c0];
            float wb[4] = {w2v.x, w2v.y, w2v.z, w2v.w};
#pragma unroll
            for (int i = 0; i < 4; ++i)
#pragma unroll
                for (int j = 0; j < 4; ++j)
                    acc2[i][j] = fmaf(xa[i], wb[j], acc2[i][j]);
        }
    }

    float4 b1v = make_float4(0.f, 0.f, 0.f, 0.f);
    if (B1) b1v = *(const float4*)&B1[c0];
#pragma unroll
    for (int i = 0; i < 4; ++i) {
        long gr = (long)blockIdx.x * 64 + r0 + i;
        if (gr < n) {
            float o0 = acc1[i][0] + b1v.x;
            float o1 = acc1[i][1] + b1v.y;
            float o2 = acc1[i][2] + b1v.z;
            float o3 = acc1[i][3] + b1v.w;
            if (relu1) { o0 = fmaxf(o0, 0.f); o1 = fmaxf(o1, 0.f); o2 = fmaxf(o2, 0.f); o3 = fmaxf(o3, 0.f); }
            if (BF1) {
                ushort4 o;
                o.x = f2bf(o0); o.y = f2bf(o1); o.z = f2bf(o2); o.w = f2bf(o3);
                *(ushort4*)((unsigned short*)C1v + gr * EMB + c0) = o;
            } else {
                *(float4*)((float*)C1v + gr * EMB + c0) = make_float4(o0, o1, o2, o3);
            }
        }
    }
    if (HAS2) {
        float4 b2v = make_float4(0.f, 0.f, 0.f, 0.f);
        if (B2) b2v = *(const float4*)&B2[c0];
#pragma unroll
        for (int i = 0; i < 4; ++i) {
            long gr = (long)blockIdx.x * 64 + r0 + i;
            if (gr < n) {
                float o0 = acc2[i][0] + b2v.x;
                float o1 = acc2[i][1] + b2v.y;
                float o2 = acc2[i][2] + b2v.z;
                float o3 = acc2[i][3] + b2v.w;
                if (relu2) { o0 = fmaxf(o0, 0.f); o1 = fmaxf(o1, 0.f); o2 = fmaxf(o2, 0.f); o3 = fmaxf(o3, 0.f); }
                *(float4*)&C2[gr * EMB + c0] = make_float4(o0, o1, o2, o3);
            }
        }
    }
}

// out[node] = relu(mean_{nbr} bf16_table[nbr] + bias + out[node])
// One node per wave. lane = 16*g + p: slot g in {0..3} takes neighbors with
// index = g (mod 4); lane loads uint2 = 8B = 4 bf16 at feature quad p.
// One wave64 load instruction covers 4 rows (512B); unroll 2 -> 8 rows in
// flight. fp32 accumulate; shfl_xor(16)+(32) reduce; g==0 lanes float4 RMW.
__global__ __launch_bounds__(256) void agg_bf16_kernel(
    const unsigned short* __restrict__ tbl, const int* __restrict__ rowptr,
    const int* __restrict__ adj, const float* __restrict__ bias,
    float* __restrict__ out, int n_dst)
{
    int lane = threadIdx.x & 63;
    int node = blockIdx.x * 4 + (threadIdx.x >> 6);
    if (node >= n_dst) return;
    int p = lane & 15;     // feature quad: bf16 [4p, 4p+4)
    int g = lane >> 4;     // neighbor slot
    int beg = rowptr[node];
    int end = rowptr[node + 1];
    const uint2* tb = (const uint2*)tbl;   // row stride = 16 uint2 (128B)
    float a0 = 0.f, a1 = 0.f, a2 = 0.f, a3 = 0.f;
    int e = beg + g;
    for (; e + 4 < end; e += 8) {
        int r0 = adj[e];
        int r1 = adj[e + 4];
        uint2 w0 = tb[(long)r0 * 16 + p];
        uint2 w1 = tb[(long)r1 * 16 + p];
        a0 += bflo(w0.x) + bflo(w1.x);
        a1 += bfhi(w0.x) + bfhi(w1.x);
        a2 += bflo(w0.y) + bflo(w1.y);
        a3 += bfhi(w0.y) + bfhi(w1.y);
    }
    if (e < end) {
        uint2 w0 = tb[(long)adj[e] * 16 + p];
        a0 += bflo(w0.x);
        a1 += bfhi(w0.x);
        a2 += bflo(w0.y);
        a3 += bfhi(w0.y);
    }
    a0 += __shfl_xor(a0, 16); a0 += __shfl_xor(a0, 32);
    a1 += __shfl_xor(a1, 16); a1 += __shfl_xor(a1, 32);
    a2 += __shfl_xor(a2, 16); a2 += __shfl_xor(a2, 32);
    a3 += __shfl_xor(a3, 16); a3 += __shfl_xor(a3, 32);
    if (g == 0) {
        int cnt = end - beg;
        float inv = 1.f / (float)(cnt > 0 ? cnt : 1);
        float4 bv = ((const float4*)bias)[p];
        float4* op = (float4*)(out + (long)node * EMB) + p;
        float4 ov = *op;
        float v0 = a0 * inv + bv.x + ov.x;
        float v1 = a1 * inv + bv.y + ov.y;
        float v2 = a2 * inv + bv.z + ov.z;
        float v3 = a3 * inv + bv.w + ov.w;
        *op = make_float4(fmaxf(v0, 0.f), fmaxf(v1, 0.f), fmaxf(v2, 0.f), fmaxf(v3, 0.f));
    }
}

extern "C" void kernel_launch(void* const* d_in, const int* in_sizes, int n_in,
                              void* d_out, int out_size, void* d_ws, size_t ws_size,
                              hipStream_t stream) {
    const float* cons_x     = (const float*)d_in[0];
    const float* var_x      = (const float*)d_in[1];
    const int*   eidx       = (const int*)d_in[3];
    const float* cons_shift = (const float*)d_in[4];
    const float* cons_scale = (const float*)d_in[5];
    const float* cons_w1    = (const float*)d_in[6];
    const float* cons_b1    = (const float*)d_in[7];
    const float* cons_w2    = (const float*)d_in[8];
    const float* cons_b2    = (const float*)d_in[9];
    const float* var_shift  = (const float*)d_in[10];
    const float* var_scale  = (const float*)d_in[11];
    const float* var_w1     = (const float*)d_in[12];
    const float* var_b1     = (const float*)d_in[13];
    const float* var_w2     = (const float*)d_in[14];
    const float* var_b2     = (const float*)d_in[15];
    const float* ll_w       = (const float*)d_in[18];
    const float* ll_b       = (const float*)d_in[19];
    const float* lr_w       = (const float*)d_in[20];

    const int nC = in_sizes[0] / 5;
    const int nV = in_sizes[1] / 19;
    const int E  = in_sizes[3] / 2;
    const int* src = eidx;       // constraint ids
    const int* dst = eidx + E;   // variable ids

    int shc = 0; while ((nC >> shc) >= 512) ++shc;
    int shv = 0; while ((nV >> shv) >= 512) ++shv;
    const int NBC = (nC + (1 << shc) - 1) >> shc;
    const int NBV = (nV + (1 << shv) - 1) >> shv;

    char* w = (char*)d_ws;
    auto alloc = [&](size_t bytes) {
        char* p = w;
        w += (bytes + 255) & ~(size_t)255;
        return p;
    };
    float* x_c = (float*)alloc((size_t)nC * EMB * 4);
    float* x_v = (float*)alloc((size_t)nV * EMB * 4);
    float* t_c = (float*)alloc((size_t)nC * EMB * 4);   // aliases: tmp_c, then bf16 table
    float* t_v = (float*)alloc((size_t)nV * EMB * 4);
    unsigned* tmp_c = (unsigned*)t_c;                   // E*4 = 8MB <= region
    unsigned* tmp_v = (unsigned*)t_v;
    unsigned short* tb_c = (unsigned short*)t_c;
    unsigned short* tb_v = (unsigned short*)t_v;
    int* rp_v  = (int*)alloc((size_t)(nV + 1) * 4);
    int* rp_c  = (int*)alloc((size_t)(nC + 1) * 4);
    int* adj_v = (int*)alloc((size_t)E * 4);
    int* adj_c = (int*)alloc((size_t)E * 4);
    int* bkt   = (int*)alloc(4096 * 4);
    int* bb_c   = bkt;
    int* bb_v   = bkt + 1024;
    int* gcur_c = bkt + 2048;
    int* gcur_v = bkt + 3072;

    auto llw = [&](int l, int d) { return ll_w + (size_t)(l * 2 + d) * EMB * EMB; };
    auto lrw = [&](int l, int d) { return lr_w + (size_t)(l * 2 + d) * EMB * EMB; };
    auto llb = [&](int l, int d) { return ll_b + (size_t)(l * 2 + d) * EMB; };

    // ---- CSR build ----
    zero_int_kernel<<<16, 256, 0, stream>>>(bkt, 4096);
    bucket_hist_kernel<<<(E + CH - 1) / CH, 256, 0, stream>>>(src, dst, E, bb_c, bb_v, shc, shv, NBC, NBV);
    scan_buckets_kernel<<<1, 256, 0, stream>>>(bb_c, NBC, bb_v, NBV, E);
    bin_edges_kernel<<<(E + CH - 1) / CH, 256, 0, stream>>>(src, dst, E, bb_c, bb_v, gcur_c, gcur_v,
                                                            tmp_c, tmp_v, shc, shv, NBC, NBV);
    regroup2_kernel<<<NBV, 256, 0, stream>>>(tmp_v, bb_v, rp_v, adj_v, nV, shv, E, NBV);
    regroup2_kernel<<<NBC, 256, 0, stream>>>(tmp_c, bb_c, rp_c, adj_c, nC, shc, E, NBC);

    // ---- node embeddings (fused MLP; tmp consumed, t_* free) ----
    fused_embed_kernel<5><<<(nC + 63) / 64, 256, 0, stream>>>(
        cons_x, cons_shift, cons_scale, cons_w1, cons_b1, cons_w2, cons_b2, x_c, nC);
    fused_embed_kernel<19><<<(nV + 63) / 64, 256, 0, stream>>>(
        var_x, var_shift, var_scale, var_w1, var_b1, var_w2, var_b2, x_v, nV);

    // ---- layer 0: t tables in bf16, u-terms fp32 in place ----
    gemm64_kernel<true, true><<<(nC + 63) / 64, 256, 0, stream>>>(x_c, nC, llw(0, 0), nullptr, 0, tb_c,
                                                                  lrw(0, 1), nullptr, 0, x_c);
    gemm64_kernel<true, true><<<(nV + 63) / 64, 256, 0, stream>>>(x_v, nV, llw(0, 1), nullptr, 0, tb_v,
                                                                  lrw(0, 0), nullptr, 0, x_v);
    agg_bf16_kernel<<<(nV + 3) / 4, 256, 0, stream>>>(tb_c, rp_v, adj_v, llb(0, 0), x_v, nV);
    agg_bf16_kernel<<<(nC + 3) / 4, 256, 0, stream>>>(tb_v, rp_c, adj_c, llb(0, 1), x_c, nC);

    // ---- layer 1 (final): only new_v reaches the output ----
    gemm64_kernel<false, true><<<(nC + 63) / 64, 256, 0, stream>>>(x_c, nC, llw(1, 0), nullptr, 0, tb_c,
                                                                   nullptr, nullptr, 0, nullptr);
    gemm64_kernel<false, false><<<(nV + 63) / 64, 256, 0, stream>>>(x_v, nV, lrw(1, 0), nullptr, 0, (float*)d_out,
                                                                    nullptr, nullptr, 0, nullptr);
    agg_bf16_kernel<<<(nV + 3) / 4, 256, 0, stream>>>(tb_c, rp_v, adj_v, llb(1, 0), (float*)d_out, nV);
}

// Round 7
// 480.347 us; speedup vs baseline: 2.0154x; 1.0399x over previous
//
#include <hip/hip_runtime.h>

#define EMB 64
#define CH 4096

// ---------------------------------------------------------------------------
// Round 7: fuse ALL dense GEMMs into their producers/consumers.
//  - embed_fused<NF>: prenorm + W1+relu + W2+relu (x-hat in LDS only) +
//    t = xhat@llw -> bf16 table + u = xhat@lrw -> f32 u-buffer. x never
//    hits HBM. Replaces fused_embed + dual-output gemm64 (saves ~154MB).
//  - agg64<BF_OUT>: 64 dst nodes per 512-thread block. Gather phase builds
//    xhat tile in LDS (mean + bias + u + relu), epilogue GEMM:
//      var side  x lrw(1,0) -> d_out (u-term for final layer)
//      cons side x llw(1,0) -> tb_c  (layer-1 table)
//    xhat_v / xhat_c never hit HBM. Replaces agg + 2 gemm64 (saves ~154MB).
//  - final agg_bf16 RMWs d_out. 11 dispatches total (was 15).
// ---------------------------------------------------------------------------

static __device__ __forceinline__ unsigned short f2bf(float x) {
    union { float f; unsigned u; } v; v.f = x;
    unsigned r = v.u + 0x7fffu + ((v.u >> 16) & 1u);   // RNE
    return (unsigned short)(r >> 16);
}
static __device__ __forceinline__ float bflo(unsigned w) {
    union { unsigned u; float f; } v; v.u = w << 16; return v.f;
}
static __device__ __forceinline__ float bfhi(unsigned w) {
    union { unsigned u; float f; } v; v.u = w & 0xffff0000u; return v.f;
}

__global__ __launch_bounds__(256) void zero_int_kernel(int* __restrict__ p, int n) {
    int i = blockIdx.x * 256 + threadIdx.x;
    if (i < n) p[i] = 0;
}

__global__ __launch_bounds__(256) void bucket_hist_kernel(
    const int* __restrict__ src, const int* __restrict__ dst, int E,
    int* __restrict__ bkt_cnt_c, int* __restrict__ bkt_cnt_v,
    int shc, int shv, int NBC, int NBV)
{
    __shared__ int hc[512], hv[512];
    int t = threadIdx.x;
    int base = blockIdx.x * CH;
    int n = min(CH, E - base);
    for (int i = t; i < NBC; i += 256) hc[i] = 0;
    for (int i = t; i < NBV; i += 256) hv[i] = 0;
    __syncthreads();
    for (int li = t; li < n; li += 256) {
        atomicAdd(&hc[src[base + li] >> shc], 1);
        atomicAdd(&hv[dst[base + li] >> shv], 1);
    }
    __syncthreads();
    for (int i = t; i < NBC; i += 256) { int c = hc[i]; if (c) atomicAdd(&bkt_cnt_c[i], c); }
    for (int i = t; i < NBV; i += 256) { int c = hv[i]; if (c) atomicAdd(&bkt_cnt_v[i], c); }
}

// one block: exclusive-scan both bucket-count arrays in place; data[n] = E
__global__ __launch_bounds__(256) void scan_buckets_kernel(
    int* __restrict__ bc, int nbc, int* __restrict__ bv, int nbv, int E)
{
    __shared__ int sc[256];
    int t = threadIdx.x;
    {
        int v0 = (2 * t < nbc) ? bc[2 * t] : 0;
        int v1 = (2 * t + 1 < nbc) ? bc[2 * t + 1] : 0;
        sc[t] = v0 + v1;
        __syncthreads();
        for (int off = 1; off < 256; off <<= 1) {
            int x = (t >= off) ? sc[t - off] : 0;
            __syncthreads();
            sc[t] += x;
            __syncthreads();
        }
        int ex = (t > 0) ? sc[t - 1] : 0;
        if (2 * t < nbc) bc[2 * t] = ex;
        if (2 * t + 1 < nbc) bc[2 * t + 1] = ex + v0;
        if (t == 0) bc[nbc] = E;
        __syncthreads();
    }
    {
        int v0 = (2 * t < nbv) ? bv[2 * t] : 0;
        int v1 = (2 * t + 1 < nbv) ? bv[2 * t + 1] : 0;
        sc[t] = v0 + v1;
        __syncthreads();
        for (int off = 1; off < 256; off <<= 1) {
            int x = (t >= off) ? sc[t - off] : 0;
            __syncthreads();
            sc[t] += x;
            __syncthreads();
        }
        int ex = (t > 0) ? sc[t - 1] : 0;
        if (2 * t < nbv) bv[2 * t] = ex;
        if (2 * t + 1 < nbv) bv[2 * t + 1] = ex + v0;
        if (t == 0) bv[nbv] = E;
    }
}

// Phase 1: per-chunk LDS binning; packed u32 {local_node<<23 | other}.
__global__ __launch_bounds__(256) void bin_edges_kernel(
    const int* __restrict__ src, const int* __restrict__ dst, int E,
    const int* __restrict__ bb_c, const int* __restrict__ bb_v,
    int* __restrict__ gcur_c, int* __restrict__ gcur_v,
    unsigned* __restrict__ tmp_c, unsigned* __restrict__ tmp_v,
    int shc, int shv, int NBC, int NBV)
{
    __shared__ int hc[512], hv[512];
    int t = threadIdx.x;
    int base = blockIdx.x * CH;
    int n = min(CH, E - base);
    unsigned mc = (1u << shc) - 1u, mv = (1u << shv) - 1u;

    for (int i = t; i < NBC; i += 256) hc[i] = 0;
    for (int i = t; i < NBV; i += 256) hv[i] = 0;
    __syncthreads();

    int ss[16], dd[16];
#pragma unroll
    for (int q = 0; q < 16; ++q) {
        int li = t + q * 256;
        bool ok = li < n;
        ss[q] = ok ? src[base + li] : -1;
        dd[q] = ok ? dst[base + li] : -1;
        if (ok) {
            atomicAdd(&hc[ss[q] >> shc], 1);
            atomicAdd(&hv[dd[q] >> shv], 1);
        }
    }
    __syncthreads();

    for (int i = t; i < NBC; i += 256) {
        int c = hc[i];
        hc[i] = c ? (bb_c[i] + atomicAdd(&gcur_c[i], c)) : 0;
    }
    for (int i = t; i < NBV; i += 256) {
        int c = hv[i];
        hv[i] = c ? (bb_v[i] + atomicAdd(&gcur_v[i], c)) : 0;
    }
    __syncthreads();

#pragma unroll
    for (int q = 0; q < 16; ++q) {
        int li = t + q * 256;
        if (li < n) {
            unsigned s = (unsigned)ss[q], d = (unsigned)dd[q];
            int pc = atomicAdd(&hc[s >> shc], 1);
            tmp_c[pc] = ((s & mc) << 23) | d;
            int pv = atomicAdd(&hv[d >> shv], 1);
            tmp_v[pv] = ((d & mv) << 23) | s;
        }
    }
}

// Phase 2: wg-per-bucket. LDS per-node hist -> scan -> rp; rank -> adj.
__global__ __launch_bounds__(256) void regroup2_kernel(
    const unsigned* __restrict__ tmp, const int* __restrict__ bb,
    int* __restrict__ rp, int* __restrict__ adj, int n_nodes, int sh, int E, int nb)
{
    __shared__ int cnt[512];
    __shared__ int offs[512];
    __shared__ int sc[256];
    int t = threadIdx.x;
    int b = blockIdx.x;
    int node0 = b << sh;
    int node1 = min(node0 + (1 << sh), n_nodes);
    int nn = node1 - node0;
    for (int i = t; i < nn; i += 256) cnt[i] = 0;
    __syncthreads();
    int beg = bb[b], end = bb[b + 1];
    for (int e = beg + t; e < end; e += 256)
        atomicAdd(&cnt[tmp[e] >> 23], 1);
    __syncthreads();
    int v0 = (2 * t < nn) ? cnt[2 * t] : 0;
    int v1 = (2 * t + 1 < nn) ? cnt[2 * t + 1] : 0;
    sc[t] = v0 + v1;
    __syncthreads();
    for (int off = 1; off < 256; off <<= 1) {
        int x = (t >= off) ? sc[t - off] : 0;
        __syncthreads();
        sc[t] += x;
        __syncthreads();
    }
    int ex = (t > 0) ? sc[t - 1] : 0;
    if (2 * t < nn) offs[2 * t] = ex;
    if (2 * t + 1 < nn) offs[2 * t + 1] = ex + v0;
    __syncthreads();
    for (int i = t; i < nn; i += 256) {
        rp[node0 + i] = beg + offs[i];
        cnt[i] = 0;
    }
    if (b == nb - 1 && t == 0) rp[n_nodes] = E;
    __syncthreads();
    for (int e = beg + t; e < end; e += 256) {
        unsigned p = tmp[e];
        int d = (int)(p >> 23);
        int r = atomicAdd(&cnt[d], 1);
        adj[beg + offs[d] + r] = (int)(p & 0x7fffffu);
    }
}

// Fully fused node pipeline:
//   xhat = relu(relu(((x+shift)*scale)@W1+b1)@W2+b2)   (LDS only)
//   tb   = bf16(xhat @ Wll)      (layer-0 gather table)
//   u    = xhat @ Wlr            (layer-0 self term, f32)
template <int NF>
__global__ __launch_bounds__(256) void embed_fused_kernel(
    const float* __restrict__ x, const float* __restrict__ shift, const float* __restrict__ scale,
    const float* __restrict__ w1, const float* __restrict__ b1,
    const float* __restrict__ w2, const float* __restrict__ b2,
    const float* __restrict__ wll, const float* __restrict__ wlr,
    unsigned short* __restrict__ tb, float* __restrict__ u, int n)
{
    __shared__ float xs[NF * 68];
    __shared__ float w1s[NF * EMB];
    __shared__ float hs[EMB * 68];    // h, then xhat (transposed [k][r])
    __shared__ float ws[EMB * EMB];   // w2 -> wll -> wlr
    __shared__ float b1s[EMB], b2s[EMB];

    int t = threadIdx.x;
    long row0 = (long)blockIdx.x * 64;
    int nrow = (int)((n - row0 < 64) ? (n - row0) : 64);

    for (int i = t; i < NF * EMB; i += 256) w1s[i] = w1[i];
    if (t < EMB) { b1s[t] = b1[t]; b2s[t] = b2[t]; }
    {
        const float4* wg = (const float4*)w2;
        float4* wl = (float4*)ws;
#pragma unroll
        for (int q = 0; q < 4; ++q) wl[t + q * 256] = wg[t + q * 256];
    }
    for (int i = t; i < 64 * NF; i += 256) {
        int r = i / NF, k = i - r * NF;
        float v = (r < nrow) ? x[row0 * NF + i] : 0.f;
        xs[k * 68 + r] = (v + shift[k]) * scale[k];
    }
    __syncthreads();

    int r0 = (t >> 4) * 4;
    int c0 = (t & 15) * 4;

    // GEMM1: h = relu(xs @ W1 + b1), stored transposed into hs
    {
        float a1[4][4] = {{0.f}};
#pragma unroll
        for (int k = 0; k < NF; ++k) {
            float4 xv = *(const float4*)&xs[k * 68 + r0];
            float4 wv = *(const float4*)&w1s[k * EMB + c0];
            float xa[4] = {xv.x, xv.y, xv.z, xv.w};
            float wa[4] = {wv.x, wv.y, wv.z, wv.w};
#pragma unroll
            for (int i = 0; i < 4; ++i)
#pragma unroll
                for (int j = 0; j < 4; ++j)
                    a1[i][j] = fmaf(xa[i], wa[j], a1[i][j]);
        }
#pragma unroll
        for (int j = 0; j < 4; ++j) {
            float b = b1s[c0 + j];
            float4 o;
            o.x = fmaxf(a1[0][j] + b, 0.f);
            o.y = fmaxf(a1[1][j] + b, 0.f);
            o.z = fmaxf(a1[2][j] + b, 0.f);
            o.w = fmaxf(a1[3][j] + b, 0.f);
            *(float4*)&hs[(c0 + j) * 68 + r0] = o;
        }
    }
    __syncthreads();

    // GEMM2: xhat = relu(h @ W2 + b2) -> regs
    float a2[4][4] = {{0.f}};
#pragma unroll 8
    for (int k = 0; k < EMB; ++k) {
        float4 xv = *(const float4*)&hs[k * 68 + r0];
        float4 wv = *(const float4*)&ws[k * EMB + c0];
        float xa[4] = {xv.x, xv.y, xv.z, xv.w};
        float wa[4] = {wv.x, wv.y, wv.z, wv.w};
#pragma unroll
        for (int i = 0; i < 4; ++i)
#pragma unroll
            for (int j = 0; j < 4; ++j)
                a2[i][j] = fmaf(xa[i], wa[j], a2[i][j]);
    }
    __syncthreads();   // all reads of hs (h) and ws (w2) complete

    // store xhat into hs (transposed) ; stage wll into ws
#pragma unroll
    for (int j = 0; j < 4; ++j) {
        float b = b2s[c0 + j];
        float4 o;
        o.x = fmaxf(a2[0][j] + b, 0.f);
        o.y = fmaxf(a2[1][j] + b, 0.f);
        o.z = fmaxf(a2[2][j] + b, 0.f);
        o.w = fmaxf(a2[3][j] + b, 0.f);
        *(float4*)&hs[(c0 + j) * 68 + r0] = o;
    }
    {
        const float4* wg = (const float4*)wll;
        float4* wl = (float4*)ws;
#pragma unroll
        for (int q = 0; q < 4; ++q) wl[t + q * 256] = wg[t + q * 256];
    }
    __syncthreads();

    // GEMM3: t = xhat @ Wll -> bf16 table
    {
        float a3[4][4] = {{0.f}};
#pragma unroll 8
        for (int k = 0; k < EMB; ++k) {
            float4 xv = *(const float4*)&hs[k * 68 + r0];
            float4 wv = *(const float4*)&ws[k * EMB + c0];
            float xa[4] = {xv.x, xv.y, xv.z, xv.w};
            float wa[4] = {wv.x, wv.y, wv.z, wv.w};
#pragma unroll
            for (int i = 0; i < 4; ++i)
#pragma unroll
                for (int j = 0; j < 4; ++j)
                    a3[i][j] = fmaf(xa[i], wa[j], a3[i][j]);
        }
#pragma unroll
        for (int i = 0; i < 4; ++i) {
            long gr = row0 + r0 + i;
            if (gr < n) {
                ushort4 o;
                o.x = f2bf(a3[i][0]); o.y = f2bf(a3[i][1]);
                o.z = f2bf(a3[i][2]); o.w = f2bf(a3[i][3]);
                *(ushort4*)(tb + gr * EMB + c0) = o;
            }
        }
    }
    __syncthreads();   // all reads of ws (wll) complete

    {
        const float4* wg = (const float4*)wlr;
        float4* wl = (float4*)ws;
#pragma unroll
        for (int q = 0; q < 4; ++q) wl[t + q * 256] = wg[t + q * 256];
    }
    __syncthreads();

    // GEMM4: u = xhat @ Wlr -> f32
    {
        float a4[4][4] = {{0.f}};
#pragma unroll 8
        for (int k = 0; k < EMB; ++k) {
            float4 xv = *(const float4*)&hs[k * 68 + r0];
            float4 wv = *(const float4*)&ws[k * EMB + c0];
            float xa[4] = {xv.x, xv.y, xv.z, xv.w};
            float wa[4] = {wv.x, wv.y, wv.z, wv.w};
#pragma unroll
            for (int i = 0; i < 4; ++i)
#pragma unroll
                for (int j = 0; j < 4; ++j)
                    a4[i][j] = fmaf(xa[i], wa[j], a4[i][j]);
        }
#pragma unroll
        for (int i = 0; i < 4; ++i) {
            long gr = row0 + r0 + i;
            if (gr < n)
                *(float4*)&u[gr * EMB + c0] = make_float4(a4[i][0], a4[i][1], a4[i][2], a4[i][3]);
        }
    }
}

// Fused layer-0 agg + layer-1 GEMM. 512 threads = 8 waves, 64 nodes/block.
// Gather: xhat[node] = relu(mean_nbr tb[nbr] + bias + u[node]) -> LDS tile.
// Epilogue GEMM: out = xhat @ W  (BF_OUT: bf16 table, else f32).
template <bool BF_OUT>
__global__ __launch_bounds__(512) void agg64_kernel(
    const unsigned short* __restrict__ tbl, const int* __restrict__ rowptr,
    const int* __restrict__ adj, const float* __restrict__ bias,
    const float* __restrict__ u, const float* __restrict__ W,
    void* __restrict__ outv, int n)
{
    __shared__ float xt[EMB * 68];   // [k][r]
    __shared__ float ws[EMB * EMB];
    __shared__ float bs[EMB];

    int t = threadIdx.x;
    long node0 = (long)blockIdx.x * 64;
    int lane = t & 63;
    int wv = t >> 6;                 // wave id 0..7
    int p = lane & 15, g = lane >> 4;
    int f = 4 * p + g;               // this lane's feature for the LDS store

    {
        const float4* wg = (const float4*)W;
        float4* wl = (float4*)ws;
        wl[t] = wg[t];
        wl[t + 512] = wg[t + 512];
    }
    if (t < EMB) bs[t] = bias[t];
    __syncthreads();

    const uint2* tb = (const uint2*)tbl;
    for (int i = 0; i < 8; ++i) {
        int node = (int)node0 + wv * 8 + i;
        float val = 0.f;
        if (node < n) {
            int beg = rowptr[node];
            int end = rowptr[node + 1];
            float a0 = 0.f, a1 = 0.f, a2 = 0.f, a3 = 0.f;
            int e = beg + g;
            for (; e + 4 < end; e += 8) {
                int r0 = adj[e];
                int r1 = adj[e + 4];
                uint2 w0 = tb[(long)r0 * 16 + p];
                uint2 w1 = tb[(long)r1 * 16 + p];
                a0 += bflo(w0.x) + bflo(w1.x);
                a1 += bfhi(w0.x) + bfhi(w1.x);
                a2 += bflo(w0.y) + bflo(w1.y);
                a3 += bfhi(w0.y) + bfhi(w1.y);
            }
            if (e < end) {
                uint2 w0 = tb[(long)adj[e] * 16 + p];
                a0 += bflo(w0.x);
                a1 += bfhi(w0.x);
                a2 += bflo(w0.y);
                a3 += bfhi(w0.y);
            }
            a0 += __shfl_xor(a0, 16); a0 += __shfl_xor(a0, 32);
            a1 += __shfl_xor(a1, 16); a1 += __shfl_xor(a1, 32);
            a2 += __shfl_xor(a2, 16); a2 += __shfl_xor(a2, 32);
            a3 += __shfl_xor(a3, 16); a3 += __shfl_xor(a3, 32);
            int cnt = end - beg;
            float inv = 1.f / (float)(cnt > 0 ? cnt : 1);
            float av = (g == 0) ? a0 : ((g == 1) ? a1 : ((g == 2) ? a2 : a3));
            val = fmaxf(av * inv + bs[f] + u[(long)node * EMB + f], 0.f);
        }
        xt[f * 68 + (wv * 8 + i)] = val;
    }
    __syncthreads();

    // GEMM: out[r][c] = sum_k xt[k][r] * ws[k][c]; 8 outputs/thread
    int c0 = (t & 15) * 4;
    int r0 = (t >> 4) * 2;
    float acc[2][4] = {{0.f}};
#pragma unroll 8
    for (int k = 0; k < EMB; ++k) {
        float2 xv = *(const float2*)&xt[k * 68 + r0];
        float4 wv4 = *(const float4*)&ws[k * EMB + c0];
        float xa[2] = {xv.x, xv.y};
        float wa[4] = {wv4.x, wv4.y, wv4.z, wv4.w};
#pragma unroll
        for (int i = 0; i < 2; ++i)
#pragma unroll
            for (int j = 0; j < 4; ++j)
                acc[i][j] = fmaf(xa[i], wa[j], acc[i][j]);
    }
#pragma unroll
    for (int i = 0; i < 2; ++i) {
        long gr = node0 + r0 + i;
        if (gr < n) {
            if (BF_OUT) {
                ushort4 o;
                o.x = f2bf(acc[i][0]); o.y = f2bf(acc[i][1]);
                o.z = f2bf(acc[i][2]); o.w = f2bf(acc[i][3]);
                *(ushort4*)((unsigned short*)outv + gr * EMB + c0) = o;
            } else {
                *(float4*)((float*)outv + gr * EMB + c0) =
                    make_float4(acc[i][0], acc[i][1], acc[i][2], acc[i][3]);
            }
        }
    }
}

// Final layer: out[node] = relu(mean_nbr tb[nbr] + bias + out[node])  (RMW)
__global__ __launch_bounds__(256) void agg_bf16_kernel(
    const unsigned short* __restrict__ tbl, const int* __restrict__ rowptr,
    const int* __restrict__ adj, const float* __restrict__ bias,
    float* __restrict__ out, int n_dst)
{
    int lane = threadIdx.x & 63;
    int node = blockIdx.x * 4 + (threadIdx.x >> 6);
    if (node >= n_dst) return;
    int p = lane & 15;
    int g = lane >> 4;
    int beg = rowptr[node];
    int end = rowptr[node + 1];
    const uint2* tb = (const uint2*)tbl;
    float a0 = 0.f, a1 = 0.f, a2 = 0.f, a3 = 0.f;
    int e = beg + g;
    for (; e + 4 < end; e += 8) {
        int r0 = adj[e];
        int r1 = adj[e + 4];
        uint2 w0 = tb[(long)r0 * 16 + p];
        uint2 w1 = tb[(long)r1 * 16 + p];
        a0 += bflo(w0.x) + bflo(w1.x);
        a1 += bfhi(w0.x) + bfhi(w1.x);
        a2 += bflo(w0.y) + bflo(w1.y);
        a3 += bfhi(w0.y) + bfhi(w1.y);
    }
    if (e < end) {
        uint2 w0 = tb[(long)adj[e] * 16 + p];
        a0 += bflo(w0.x);
        a1 += bfhi(w0.x);
        a2 += bflo(w0.y);
        a3 += bfhi(w0.y);
    }
    a0 += __shfl_xor(a0, 16); a0 += __shfl_xor(a0, 32);
    a1 += __shfl_xor(a1, 16); a1 += __shfl_xor(a1, 32);
    a2 += __shfl_xor(a2, 16); a2 += __shfl_xor(a2, 32);
    a3 += __shfl_xor(a3, 16); a3 += __shfl_xor(a3, 32);
    if (g == 0) {
        int cnt = end - beg;
        float inv = 1.f / (float)(cnt > 0 ? cnt : 1);
        float4 bv = ((const float4*)bias)[p];
        float4* op = (float4*)(out + (long)node * EMB) + p;
        float4 ov = *op;
        float v0 = a0 * inv + bv.x + ov.x;
        float v1 = a1 * inv + bv.y + ov.y;
        float v2 = a2 * inv + bv.z + ov.z;
        float v3 = a3 * inv + bv.w + ov.w;
        *op = make_float4(fmaxf(v0, 0.f), fmaxf(v1, 0.f), fmaxf(v2, 0.f), fmaxf(v3, 0.f));
    }
}

extern "C" void kernel_launch(void* const* d_in, const int* in_sizes, int n_in,
                              void* d_out, int out_size, void* d_ws, size_t ws_size,
                              hipStream_t stream) {
    const float* cons_x     = (const float*)d_in[0];
    const float* var_x      = (const float*)d_in[1];
    const int*   eidx       = (const int*)d_in[3];
    const float* cons_shift = (const float*)d_in[4];
    const float* cons_scale = (const float*)d_in[5];
    const float* cons_w1    = (const float*)d_in[6];
    const float* cons_b1    = (const float*)d_in[7];
    const float* cons_w2    = (const float*)d_in[8];
    const float* cons_b2    = (const float*)d_in[9];
    const float* var_shift  = (const float*)d_in[10];
    const float* var_scale  = (const float*)d_in[11];
    const float* var_w1     = (const float*)d_in[12];
    const float* var_b1     = (const float*)d_in[13];
    const float* var_w2     = (const float*)d_in[14];
    const float* var_b2     = (const float*)d_in[15];
    const float* ll_w       = (const float*)d_in[18];
    const float* ll_b       = (const float*)d_in[19];
    const float* lr_w       = (const float*)d_in[20];

    const int nC = in_sizes[0] / 5;
    const int nV = in_sizes[1] / 19;
    const int E  = in_sizes[3] / 2;
    const int* src = eidx;       // constraint ids
    const int* dst = eidx + E;   // variable ids

    int shc = 0; while ((nC >> shc) >= 512) ++shc;
    int shv = 0; while ((nV >> shv) >= 512) ++shv;
    const int NBC = (nC + (1 << shc) - 1) >> shc;
    const int NBV = (nV + (1 << shv) - 1) >> shv;

    char* w = (char*)d_ws;
    auto alloc = [&](size_t bytes) {
        char* p = w;
        w += (bytes + 255) & ~(size_t)255;
        return p;
    };
    float* x_c = (float*)alloc((size_t)nC * EMB * 4);   // u_c buffer
    float* x_v = (float*)alloc((size_t)nV * EMB * 4);   // u_v buffer
    float* t_c = (float*)alloc((size_t)nC * EMB * 4);   // aliases: tmp_c, then bf16 table tb_c
    float* t_v = (float*)alloc((size_t)nV * EMB * 4);
    unsigned* tmp_c = (unsigned*)t_c;
    unsigned* tmp_v = (unsigned*)t_v;
    unsigned short* tb_c = (unsigned short*)t_c;
    unsigned short* tb_v = (unsigned short*)t_v;
    int* rp_v  = (int*)alloc((size_t)(nV + 1) * 4);
    int* rp_c  = (int*)alloc((size_t)(nC + 1) * 4);
    int* adj_v = (int*)alloc((size_t)E * 4);
    int* adj_c = (int*)alloc((size_t)E * 4);
    int* bkt   = (int*)alloc(4096 * 4);
    int* bb_c   = bkt;
    int* bb_v   = bkt + 1024;
    int* gcur_c = bkt + 2048;
    int* gcur_v = bkt + 3072;

    auto llw = [&](int l, int d) { return ll_w + (size_t)(l * 2 + d) * EMB * EMB; };
    auto lrw = [&](int l, int d) { return lr_w + (size_t)(l * 2 + d) * EMB * EMB; };
    auto llb = [&](int l, int d) { return ll_b + (size_t)(l * 2 + d) * EMB; };

    // ---- CSR build ----
    zero_int_kernel<<<16, 256, 0, stream>>>(bkt, 4096);
    bucket_hist_kernel<<<(E + CH - 1) / CH, 256, 0, stream>>>(src, dst, E, bb_c, bb_v, shc, shv, NBC, NBV);
    scan_buckets_kernel<<<1, 256, 0, stream>>>(bb_c, NBC, bb_v, NBV, E);
    bin_edges_kernel<<<(E + CH - 1) / CH, 256, 0, stream>>>(src, dst, E, bb_c, bb_v, gcur_c, gcur_v,
                                                            tmp_c, tmp_v, shc, shv, NBC, NBV);
    regroup2_kernel<<<NBV, 256, 0, stream>>>(tmp_v, bb_v, rp_v, adj_v, nV, shv, E, NBV);
    regroup2_kernel<<<NBC, 256, 0, stream>>>(tmp_c, bb_c, rp_c, adj_c, nC, shc, E, NBC);

    // ---- fused embed + layer-0 GEMMs (x never hits HBM) ----
    embed_fused_kernel<5><<<(nC + 63) / 64, 256, 0, stream>>>(
        cons_x, cons_shift, cons_scale, cons_w1, cons_b1, cons_w2, cons_b2,
        llw(0, 0), lrw(0, 1), tb_c, x_c, nC);
    embed_fused_kernel<19><<<(nV + 63) / 64, 256, 0, stream>>>(
        var_x, var_shift, var_scale, var_w1, var_b1, var_w2, var_b2,
        llw(0, 1), lrw(0, 0), tb_v, x_v, nV);

    // ---- layer-0 agg fused with layer-1 GEMM ----
    // var side: xhat_v @ lrw(1,0) -> d_out (u-term for final layer)
    agg64_kernel<false><<<(nV + 63) / 64, 512, 0, stream>>>(
        tb_c, rp_v, adj_v, llb(0, 0), x_v, lrw(1, 0), d_out, nV);
    // cons side: xhat_c @ llw(1,0) -> tb_c (layer-1 table, overwrite)
    agg64_kernel<true><<<(nC + 63) / 64, 512, 0, stream>>>(
        tb_v, rp_c, adj_c, llb(0, 1), x_c, llw(1, 0), tb_c, nC);

    // ---- final layer-1 var agg (RMW d_out) ----
    agg_bf16_kernel<<<(nV + 3) / 4, 256, 0, stream>>>(tb_c, rp_v, adj_v, llb(1, 0), (float*)d_out, nV);
}